// Round 5
// baseline (3418.396 us; speedup 1.0000x reference)
//
#include <hip/hip_runtime.h>
#include <hip/hip_bf16.h>

// ---------------- problem shape ----------------
#define TT 64
#define BB 256
#define DD 1024
#define HH 1024
#define G4 4096    // 4*H
#define CHT 16     // xg chunk length (timesteps); 4 chunks cover T=64

typedef __bf16 bf16x8 __attribute__((ext_vector_type(8)));
typedef float  f32x4  __attribute__((ext_vector_type(4)));

// ---------------- static device scratch (~119 MB, proven size) ----------------
__device__ unsigned short g_seq [(size_t)TT * BB * 1024];  // x (bf16) -> layer-1 h seq   32 MB
__device__ unsigned short g_Wih [(size_t)2 * G4 * 1024];   // 16 MB
__device__ unsigned short g_Whh [(size_t)2 * G4 * 1024];   // 16 MB
__device__ unsigned short g_Wfh [(size_t)2 * G4 * 1024];   // 16 MB
__device__ unsigned short g_feat[(size_t)BB * 1024];       // 0.5 MB
__device__ unsigned short g_xg  [(size_t)CHT * BB * G4];   // bf16 gates chunk            32 MB
__device__ unsigned short g_h   [2][(size_t)BB * HH];      // h state ping-pong (bf16)     1 MB
__device__ float          g_featb[(size_t)BB * G4];        // f32 feat@Wfh^T + b           4 MB
__device__ float          g_c   [(size_t)BB * HH];         // f32 cell state               1 MB

// distributed barrier flags: [bh group 0..3][jg block 0..63][64B pad].
// Monotonic epochs (never reset -> graph-replay safe); one cacheline per
// block -> parallel arrivals, parallel 64-lane polls (R4-proven pattern).
__device__ unsigned g_arrive[4][64][16];

__device__ __forceinline__ bf16x8 ld8(const __hip_bfloat16* p) {
    return *reinterpret_cast<const bf16x8*>(p);
}
__device__ __forceinline__ __hip_bfloat16* BP(unsigned short* p) {
    return reinterpret_cast<__hip_bfloat16*>(p);
}
__device__ __forceinline__ const __hip_bfloat16* BPc(const unsigned short* p) {
    return reinterpret_cast<const __hip_bfloat16*>(p);
}
__device__ __forceinline__ f32x4 MF(bf16x8 a, bf16x8 b, f32x4 c) {
    return __builtin_amdgcn_mfma_f32_16x16x32_bf16(a, b, c, 0, 0, 0);
}
__device__ __forceinline__ float fsig(float x) {
    return 1.0f / (1.0f + __expf(-x));
}
__device__ __forceinline__ float ftanh(float x) {   // clamped: exp never inf
    const float x2 = fminf(fmaxf(2.0f * x, -30.0f), 30.0f);
    const float e  = __expf(x2);
    return (e - 1.0f) / (e + 1.0f);
}

// direct global->LDS async copy, 16B per lane
typedef unsigned int u32_g __attribute__((address_space(1)));
typedef unsigned int u32_l __attribute__((address_space(3)));
__device__ __forceinline__ void gload16(const void* g, void* l) {
    __builtin_amdgcn_global_load_lds((const u32_g*)g, (u32_l*)l, 16, 0, 0);
}

// =============================================================
// f32 -> bf16 conversion into a selected device-global buffer.
// =============================================================
__global__ __launch_bounds__(256) void cvt_bf16(int which,
                                                const float* __restrict__ s,
                                                size_t n)
{
    size_t i = ((size_t)blockIdx.x * 256 + threadIdx.x) * 4;
    if (i >= n) return;
    unsigned short* d = (which == 0) ? g_seq
                      : (which == 1) ? g_Wih
                      : (which == 2) ? g_Whh
                      : (which == 3) ? g_Wfh : g_feat;
    float4 v = *reinterpret_cast<const float4*>(s + i);
    __hip_bfloat16* db = BP(d) + i;
    db[0] = __float2bfloat16(v.x);
    db[1] = __float2bfloat16(v.y);
    db[2] = __float2bfloat16(v.z);
    db[3] = __float2bfloat16(v.w);
}

// =============================================================
// Small-M featb GEMM: g_featb[256,4096] = feat @ Wfh[l]^T + b[l] (f32)
// =============================================================
__global__ __launch_bounds__(256) void gemm_featb(size_t w_off,
                                                  const float* __restrict__ bias)
{
    const int tid  = threadIdx.x;
    const int lane = tid & 63, wid = tid >> 6;
    const int row  = lane & 15, quad = lane >> 4;
    const int m_base = blockIdx.y * 128 + (wid >> 1) * 64;
    const int n_base = blockIdx.x * 64  + (wid & 1) * 32;

    const __hip_bfloat16* A = BPc(g_feat);
    const __hip_bfloat16* W = BPc(g_Wfh) + w_off;

    f32x4 acc[4][2] = {};
    const __hip_bfloat16* Ap = A + (size_t)(m_base + row) * 1024 + quad * 8;
    const __hip_bfloat16* Wp = W + (size_t)(n_base + row) * 1024 + quad * 8;

    for (int k0 = 0; k0 < 1024; k0 += 32) {
        bf16x8 a[4], b[2];
#pragma unroll
        for (int i = 0; i < 4; ++i) a[i] = ld8(Ap + (size_t)(16 * i) * 1024 + k0);
#pragma unroll
        for (int j = 0; j < 2; ++j) b[j] = ld8(Wp + (size_t)(16 * j) * 1024 + k0);
#pragma unroll
        for (int i = 0; i < 4; ++i)
#pragma unroll
            for (int j = 0; j < 2; ++j)
                acc[i][j] = MF(a[i], b[j], acc[i][j]);
    }
#pragma unroll
    for (int i = 0; i < 4; ++i)
#pragma unroll
        for (int j = 0; j < 2; ++j) {
            const int n = n_base + 16 * j + row;
#pragma unroll
            for (int r = 0; r < 4; ++r) {
                const int m = m_base + 16 * i + quad * 4 + r;
                g_featb[(size_t)m * G4 + n] = acc[i][j][r] + bias[n];
            }
        }
}

// =============================================================
// xg GEMM (chunk): C[4096,4096] = g_seq[chunk] @ Wih[l]^T  (+featb, ->bf16)
// 128x128 tile, BK=32, double-buffered LDS via global_load_lds(16B).
// Involutive both-sides LDS swizzle (R4-verified: conflicts 4.19M -> ~0).
// R5: + XCD-aware bijective block swizzle (nwg=1024, %8==0; guide T1).
// =============================================================
__global__ __launch_bounds__(256) void gemm_xg(size_t seq_off, size_t w_off)
{
    __shared__ unsigned short lA[2][128 * 32];
    __shared__ unsigned short lB[2][128 * 32];

    const int tid  = threadIdx.x;
    const int lane = tid & 63, wv = tid >> 6;
    const int row  = lane & 15, quad = lane >> 4;
    const int wr = wv >> 1, wc = wv & 1;

    // XCD swizzle: consecutive tiles land on the same XCD's L2
    const int flat = blockIdx.y * gridDim.x + blockIdx.x;
    const int cpx  = (gridDim.x * gridDim.y) >> 3;
    const int swz  = (flat & 7) * cpx + (flat >> 3);
    const int m_base = (swz / gridDim.x) * 128;
    const int n_base = (swz % gridDim.x) * 128;

    const __hip_bfloat16* A  = BPc(g_seq) + seq_off + (size_t)m_base * 1024;
    const __hip_bfloat16* Wt = BPc(g_Wih) + w_off   + (size_t)n_base * 1024;

    f32x4 acc[4][4] = {};

    const int sm = (tid >> 3) & 7;                   // == (d>>3)&7 for d=it*256+tid
    auto STAGE = [&](int bf, int kt) {
        const int k0 = kt * 32;
#pragma unroll
        for (int it = 0; it < 2; ++it) {
            const int d = it * 256 + tid;
            const int l = d ^ sm;                    // involutive granule permutation
            const int r  = l >> 2;
            const int kc = k0 + (l & 3) * 8;
            unsigned short* dA = &lA[bf][(size_t)(it * 256 + wv * 64) * 8];
            unsigned short* dB = &lB[bf][(size_t)(it * 256 + wv * 64) * 8];
            gload16(A  + (size_t)r * 1024 + kc, dA);
            gload16(Wt + (size_t)r * 1024 + kc, dB);
        }
    };

    STAGE(0, 0);
    asm volatile("s_waitcnt vmcnt(0)" ::: "memory");
    __syncthreads();

    const int rm = (row >> 1) & 7;                   // == (s>>3)&7 for our read slots

    for (int kt = 0; kt < 32; ++kt) {
        const int cur = kt & 1;
        if (kt + 1 < 32) STAGE(cur ^ 1, kt + 1);

        bf16x8 a[4], b[4];
#pragma unroll
        for (int i = 0; i < 4; ++i) {
            const int s = ((wr * 64 + 16 * i + row) * 4 + quad) ^ rm;
            a[i] = ld8(BPc(&lA[cur][(size_t)s * 8]));
        }
#pragma unroll
        for (int j = 0; j < 4; ++j) {
            const int s = ((wc * 64 + 16 * j + row) * 4 + quad) ^ rm;
            b[j] = ld8(BPc(&lB[cur][(size_t)s * 8]));
        }
#pragma unroll
        for (int i = 0; i < 4; ++i)
#pragma unroll
            for (int j = 0; j < 4; ++j)
                acc[i][j] = MF(a[i], b[j], acc[i][j]);

        asm volatile("s_waitcnt vmcnt(0)" ::: "memory");
        __syncthreads();
    }

#pragma unroll
    for (int i = 0; i < 4; ++i)
#pragma unroll
        for (int j = 0; j < 4; ++j) {
            const int n = n_base + wc * 64 + 16 * j + row;
#pragma unroll
            for (int r = 0; r < 4; ++r) {
                const int m = m_base + wr * 64 + 16 * i + quad * 4 + r;
                float v = acc[i][j][r] + g_featb[(size_t)(m & 255) * G4 + n];
                BP(g_xg)[(size_t)m * G4 + n] = __float2bfloat16(v);
            }
        }
}

// =============================================================
// Persistent LSTM chunk: 16 timesteps in ONE launch.
// R5: grid 256 blocks x 512 thr (ALL 256 CUs; R4 used only 128).
// Block (jg 0..63, bh 0..3): j-cols [jg*16,+16), batches [bh*64,+64).
// Per-CU LDS read traffic HALVES vs R4 (512 KB/block/step): wave (mg,kh) =
// batch-16 group x kt-half; per wave 16 kt x {1 global A-frag ld8,
// 4 LDS B-frags, 4 MFMA}. kt-halves reduced via 2-phase gsum add.
// Whh slice (128 KB) fragment-ordered in LDS, loaded once per chunk:
// granule G = g*2048+kt*64+l holds Whh[g*1024+j0+(l&15)][kt*32+(l>>4)*8..+8]
// -> every ds_read = base + lane*16 + imm: conflict-free.
// xg prefetched into regs at step start (latency hidden under MFMA).
// Group barrier: distributed arrive-flags per bh-group (64 blocks),
// R4-proven release/acquire pattern, monotone epochs.
// =============================================================
__global__ __launch_bounds__(512, 1) void lstm_chunk(
    const int* __restrict__ length,
    float* __restrict__ out,          // (T,B,H) f32 base (layer-1 writes)
    int c0, int layer)
{
    __shared__ unsigned short WL[64 * 1024];   // 128 KB fragment-ordered Whh
    __shared__ float gsum[64][65];             // 16.6 KB padded exchange
    __shared__ int   slen[64];                 // lengths for this block's batches
    __shared__ unsigned s_base;

    const int tid  = threadIdx.x;
    const int lane = tid & 63, wv = tid >> 6;
    const int row  = lane & 15, quad = lane >> 4;
    const int mg = wv >> 1, kh = wv & 1;       // batch-16 group, kt-half
    const int jg = blockIdx.x >> 2, bh = blockIdx.x & 3;
    const int j0 = jg * 16;
    const int bb0 = bh * 64;

    if (tid == 0)
        s_base = __hip_atomic_load(&g_arrive[bh][jg][0], __ATOMIC_RELAXED,
                                   __HIP_MEMORY_SCOPE_AGENT);
    if (tid < 64) slen[tid] = length[bb0 + tid];

    {   // ---- load Whh slice, fragment-ordered (once per chunk) ----
        const __hip_bfloat16* Whh = BPc(g_Whh) + (size_t)layer * G4 * 1024;
#pragma unroll
        for (int i = 0; i < 16; ++i) {
            const int G = tid + i * 512;                 // 0..8191 granules
            const int g = G >> 11, kt = (G >> 6) & 31, l = G & 63;
            *reinterpret_cast<bf16x8*>(&WL[(size_t)G * 8]) =
                ld8(Whh + (size_t)(g * 1024 + j0 + (l & 15)) * 1024
                        + kt * 32 + (l >> 4) * 8);
        }
    }
    __syncthreads();
    const unsigned base = s_base;

    for (int s = 0; s < CHT; ++s) {
        const int t = c0 + s;
        const __hip_bfloat16* h_in = (t > 0) ? BPc(g_h[(t + 1) & 1]) : nullptr;
        __hip_bfloat16* h_out = BP(g_h[t & 1]);
        const __hip_bfloat16* xg = BPc(g_xg) + (size_t)s * BB * G4;

        // ---- prefetch this step's xg values (consumed in elementwise) ----
        float xp[2][4];
#pragma unroll
        for (int it = 0; it < 2; ++it) {
            const int e = tid + it * 512;
            const int lb = e >> 4, lj = e & 15;
            const size_t xb = (size_t)(bb0 + lb) * G4 + j0 + lj;
            xp[it][0] = (float)xg[xb];
            xp[it][1] = (float)xg[xb + HH];
            xp[it][2] = (float)xg[xb + 2 * HH];
            xp[it][3] = (float)xg[xb + 3 * HH];
        }

        f32x4 acc[4] = {};          // 4 gates, 16 batches, this kt-half
        if (h_in) {
            const __hip_bfloat16* ap =
                h_in + (size_t)(bb0 + mg * 16 + row) * HH + kh * 512 + quad * 8;
            const unsigned short* wl = &WL[(size_t)(kh * 1024 + lane) * 8];
#pragma unroll 8
            for (int kt = 0; kt < 16; ++kt) {
                bf16x8 af = ld8(ap + kt * 32);
                acc[0] = MF(af, *(const bf16x8*)(wl + (size_t)(0 * 16384 + kt * 512)), acc[0]);
                acc[1] = MF(af, *(const bf16x8*)(wl + (size_t)(1 * 16384 + kt * 512)), acc[1]);
                acc[2] = MF(af, *(const bf16x8*)(wl + (size_t)(2 * 16384 + kt * 512)), acc[2]);
                acc[3] = MF(af, *(const bf16x8*)(wl + (size_t)(3 * 16384 + kt * 512)), acc[3]);
            }
        }

        // ---- 2-phase kt-half reduction into gsum ----
        if (kh == 0) {
#pragma unroll
            for (int g = 0; g < 4; ++g)
#pragma unroll
                for (int r = 0; r < 4; ++r)
                    gsum[mg * 16 + quad * 4 + r][g * 16 + row] = acc[g][r];
        }
        __syncthreads();
        if (kh == 1) {
#pragma unroll
            for (int g = 0; g < 4; ++g)
#pragma unroll
                for (int r = 0; r < 4; ++r)
                    gsum[mg * 16 + quad * 4 + r][g * 16 + row] += acc[g][r];
        }
        __syncthreads();

        // ---- elementwise update (64 batches x 16 j = 1024 elems) ----
#pragma unroll
        for (int it = 0; it < 2; ++it) {
            const int e = tid + it * 512;
            const int lb = e >> 4, lj = e & 15;
            const int b = bb0 + lb, j = j0 + lj;
            const float gi = gsum[lb][ 0 + lj] + xp[it][0];
            const float gf = gsum[lb][16 + lj] + xp[it][1];
            const float gg = gsum[lb][32 + lj] + xp[it][2];
            const float go = gsum[lb][48 + lj] + xp[it][3];
            const size_t idx = (size_t)b * HH + j;
            float hv;
            if (t < slen[lb]) {
                const float c_old = g_c[idx];
                const float c_new = fsig(gf) * c_old + fsig(gi) * ftanh(gg);
                g_c[idx] = c_new;
                hv = fsig(go) * ftanh(c_new);
            } else {
                hv = h_in ? (float)h_in[idx] : 0.0f;   // frozen past seq end
            }
            const __hip_bfloat16 hb = __float2bfloat16(hv);
            h_out[idx] = hb;
            if (layer == 0) BP(g_seq)[(size_t)t * BB * HH + idx] = hb;
            else            out[(size_t)t * BB * HH + idx] = hv;
        }

        // ---- distributed group barrier between steps (not after the last) ----
        if (s + 1 < CHT) {
            __syncthreads();   // all elementwise writes issued+drained (vmcnt0 @ barrier)
            const unsigned want = base + (unsigned)s + 1u;
            if (tid == 0) {
                __threadfence();                           // release this step's writes
                __hip_atomic_store(&g_arrive[bh][jg][0], want,
                                   __ATOMIC_RELAXED, __HIP_MEMORY_SCOPE_AGENT);
            }
            if (wv == 0) {                                 // lane l watches block l
                unsigned v;
                do {
                    v = __hip_atomic_load(&g_arrive[bh][lane][0],
                                          __ATOMIC_RELAXED, __HIP_MEMORY_SCOPE_AGENT);
                    if (v < want) __builtin_amdgcn_s_sleep(2);
                } while (__any(v < want));
                __threadfence();                           // acquire side
            }
            __syncthreads();
        }
    }
}

// ---------------- small utility kernels ----------------
__global__ __launch_bounds__(256) void zero_c() {
    g_c[blockIdx.x * 256 + threadIdx.x] = 0.0f;
}
__global__ __launch_bounds__(256) void finish_layer(float* __restrict__ hn,
                                                    float* __restrict__ cn)
{
    const int i = blockIdx.x * 256 + threadIdx.x;
    hn[i] = (float)BPc(g_h[(TT - 1) & 1])[i];
    cn[i] = g_c[i];
}

// =============================================================
// host launcher — plain kernel launches ONLY (graph-capture safe)
// =============================================================
extern "C" void kernel_launch(void* const* d_in, const int* in_sizes, int n_in,
                              void* d_out, int out_size, void* d_ws, size_t ws_size,
                              hipStream_t stream)
{
    const float* x        = (const float*)d_in[0];  // (T,B,D)   f32
    const float* features = (const float*)d_in[1];  // (B,F)     f32
    const float* Wih      = (const float*)d_in[2];  // (L,4H,D)  f32
    const float* Whh      = (const float*)d_in[3];  // (L,4H,H)  f32
    const float* Wfh      = (const float*)d_in[4];  // (L,4H,F)  f32
    const float* bvec     = (const float*)d_in[5];  // (L,4H)    f32
    const int*   length   = (const int*)d_in[6];    // (B,)
    float* out = (float*)d_out;                     // f32 outputs

    const size_t nX = (size_t)TT * BB * DD;
    const size_t nW = (size_t)2 * G4 * 1024;
    const size_t nF = (size_t)BB * 1024;
    cvt_bf16<<<(int)(nX / 1024), 256, 0, stream>>>(0, x, nX);
    cvt_bf16<<<(int)(nW / 1024), 256, 0, stream>>>(1, Wih, nW);
    cvt_bf16<<<(int)(nW / 1024), 256, 0, stream>>>(2, Whh, nW);
    cvt_bf16<<<(int)(nW / 1024), 256, 0, stream>>>(3, Wfh, nW);
    cvt_bf16<<<(int)(nF / 1024), 256, 0, stream>>>(4, features, nF);

    float* out_hn = out + (size_t)TT * BB * HH;
    float* out_cn = out_hn + (size_t)2 * BB * HH;

    for (int l = 0; l < 2; ++l) {
        const size_t w_off = (size_t)l * G4 * 1024;

        gemm_featb<<<dim3(G4 / 64, BB / 128), 256, 0, stream>>>(
            w_off, bvec + (size_t)l * G4);
        zero_c<<<BB * HH / 256, 256, 0, stream>>>();

        for (int c0 = 0; c0 < TT; c0 += CHT) {
            // g_xg = g_seq[chunk] @ Wih[l]^T + g_featb   (bf16 [CHT*B,4H])
            gemm_xg<<<dim3(G4 / 128, CHT * BB / 128), 256, 0, stream>>>(
                (size_t)c0 * BB * DD, w_off);

            // 16 recurrent steps, one persistent launch with group barriers
            lstm_chunk<<<256, 512, 0, stream>>>(length, out, c0, l);
        }

        finish_layer<<<BB * HH / 256, 256, 0, stream>>>(
            out_hn + (size_t)l * BB * HH, out_cn + (size_t)l * BB * HH);
    }
}

// Round 6
// 3227.585 us; speedup vs baseline: 1.0591x; 1.0591x over previous
//
#include <hip/hip_runtime.h>
#include <hip/hip_bf16.h>

// ---------------- problem shape ----------------
#define TT 64
#define BB 256
#define DD 1024
#define HH 1024
#define G4 4096    // 4*H
#define CHT 16     // xg chunk length (timesteps); 4 chunks cover T=64

typedef __bf16 bf16x8 __attribute__((ext_vector_type(8)));
typedef float  f32x4  __attribute__((ext_vector_type(4)));

// ---------------- static device scratch (~119 MB, proven size) ----------------
__device__ unsigned short g_seq [(size_t)TT * BB * 1024];  // x (bf16) -> layer-1 h seq   32 MB
__device__ unsigned short g_Wih [(size_t)2 * G4 * 1024];   // 16 MB
__device__ unsigned short g_Whh [(size_t)2 * G4 * 1024];   // 16 MB
__device__ unsigned short g_Wfh [(size_t)2 * G4 * 1024];   // 16 MB
__device__ unsigned short g_feat[(size_t)BB * 1024];       // 0.5 MB
__device__ unsigned short g_xg  [(size_t)CHT * BB * G4];   // bf16 gates chunk (GATE-INTERLEAVED: [m][j*4+g])
__device__ unsigned short g_h   [2][(size_t)BB * HH];      // h state ping-pong (bf16)     1 MB
__device__ float          g_featb[(size_t)BB * G4];        // f32 feat@Wfh^T + b           4 MB
__device__ float          g_c   [(size_t)BB * HH];         // f32 cell state               1 MB

// distributed barrier flags: [bh group 0..3][jg block 0..63][64B pad].
// Monotonic epochs (never reset -> graph-replay safe); one cacheline per
// block -> parallel arrivals, parallel 64-lane polls (R4/R5-proven pattern).
__device__ unsigned g_arrive[4][64][16];

__device__ __forceinline__ bf16x8 ld8(const __hip_bfloat16* p) {
    return *reinterpret_cast<const bf16x8*>(p);
}
__device__ __forceinline__ __hip_bfloat16* BP(unsigned short* p) {
    return reinterpret_cast<__hip_bfloat16*>(p);
}
__device__ __forceinline__ const __hip_bfloat16* BPc(const unsigned short* p) {
    return reinterpret_cast<const __hip_bfloat16*>(p);
}
__device__ __forceinline__ f32x4 MF(bf16x8 a, bf16x8 b, f32x4 c) {
    return __builtin_amdgcn_mfma_f32_16x16x32_bf16(a, b, c, 0, 0, 0);
}
__device__ __forceinline__ float fsig(float x) {
    return 1.0f / (1.0f + __expf(-x));
}
__device__ __forceinline__ float ftanh(float x) {   // clamped: exp never inf
    const float x2 = fminf(fmaxf(2.0f * x, -30.0f), 30.0f);
    const float e  = __expf(x2);
    return (e - 1.0f) / (e + 1.0f);
}
__device__ __forceinline__ float bfu2f(unsigned short u) {  // bf16 bits -> f32
    return __uint_as_float((unsigned)u << 16);
}

// direct global->LDS async copy, 16B per lane
typedef unsigned int u32_g __attribute__((address_space(1)));
typedef unsigned int u32_l __attribute__((address_space(3)));
__device__ __forceinline__ void gload16(const void* g, void* l) {
    __builtin_amdgcn_global_load_lds((const u32_g*)g, (u32_l*)l, 16, 0, 0);
}

// =============================================================
// f32 -> bf16 conversion into a selected device-global buffer.
// =============================================================
__global__ __launch_bounds__(256) void cvt_bf16(int which,
                                                const float* __restrict__ s,
                                                size_t n)
{
    size_t i = ((size_t)blockIdx.x * 256 + threadIdx.x) * 4;
    if (i >= n) return;
    unsigned short* d = (which == 0) ? g_seq
                      : (which == 1) ? g_Wih
                      : (which == 2) ? g_Whh
                      : (which == 3) ? g_Wfh : g_feat;
    float4 v = *reinterpret_cast<const float4*>(s + i);
    __hip_bfloat16* db = BP(d) + i;
    db[0] = __float2bfloat16(v.x);
    db[1] = __float2bfloat16(v.y);
    db[2] = __float2bfloat16(v.z);
    db[3] = __float2bfloat16(v.w);
}

// =============================================================
// Small-M featb GEMM: g_featb[256,4096] = feat @ Wfh[l]^T + b[l] (f32)
// =============================================================
__global__ __launch_bounds__(256) void gemm_featb(size_t w_off,
                                                  const float* __restrict__ bias)
{
    const int tid  = threadIdx.x;
    const int lane = tid & 63, wid = tid >> 6;
    const int row  = lane & 15, quad = lane >> 4;
    const int m_base = blockIdx.y * 128 + (wid >> 1) * 64;
    const int n_base = blockIdx.x * 64  + (wid & 1) * 32;

    const __hip_bfloat16* A = BPc(g_feat);
    const __hip_bfloat16* W = BPc(g_Wfh) + w_off;

    f32x4 acc[4][2] = {};
    const __hip_bfloat16* Ap = A + (size_t)(m_base + row) * 1024 + quad * 8;
    const __hip_bfloat16* Wp = W + (size_t)(n_base + row) * 1024 + quad * 8;

    for (int k0 = 0; k0 < 1024; k0 += 32) {
        bf16x8 a[4], b[2];
#pragma unroll
        for (int i = 0; i < 4; ++i) a[i] = ld8(Ap + (size_t)(16 * i) * 1024 + k0);
#pragma unroll
        for (int j = 0; j < 2; ++j) b[j] = ld8(Wp + (size_t)(16 * j) * 1024 + k0);
#pragma unroll
        for (int i = 0; i < 4; ++i)
#pragma unroll
            for (int j = 0; j < 2; ++j)
                acc[i][j] = MF(a[i], b[j], acc[i][j]);
    }
#pragma unroll
    for (int i = 0; i < 4; ++i)
#pragma unroll
        for (int j = 0; j < 2; ++j) {
            const int n = n_base + 16 * j + row;
#pragma unroll
            for (int r = 0; r < 4; ++r) {
                const int m = m_base + 16 * i + quad * 4 + r;
                g_featb[(size_t)m * G4 + n] = acc[i][j][r] + bias[n];
            }
        }
}

// =============================================================
// xg GEMM (chunk): C[4096,4096] = g_seq[chunk] @ Wih[l]^T  (+featb, ->bf16)
// 128x128 tile, BK=32, double-buffered LDS via global_load_lds(16B).
// Involutive both-sides LDS swizzle (R4-verified) + XCD block swizzle.
// R6: epilogue writes GATE-INTERLEAVED g_xg[m][(n&1023)*4 + (n>>10)] so the
// lstm step loads all 4 gates of an element as one 8B ushort4.
// =============================================================
__global__ __launch_bounds__(256) void gemm_xg(size_t seq_off, size_t w_off)
{
    __shared__ unsigned short lA[2][128 * 32];
    __shared__ unsigned short lB[2][128 * 32];

    const int tid  = threadIdx.x;
    const int lane = tid & 63, wv = tid >> 6;
    const int row  = lane & 15, quad = lane >> 4;
    const int wr = wv >> 1, wc = wv & 1;

    // XCD swizzle: consecutive tiles land on the same XCD's L2
    const int flat = blockIdx.y * gridDim.x + blockIdx.x;
    const int cpx  = (gridDim.x * gridDim.y) >> 3;
    const int swz  = (flat & 7) * cpx + (flat >> 3);
    const int m_base = (swz / gridDim.x) * 128;
    const int n_base = (swz % gridDim.x) * 128;

    const __hip_bfloat16* A  = BPc(g_seq) + seq_off + (size_t)m_base * 1024;
    const __hip_bfloat16* Wt = BPc(g_Wih) + w_off   + (size_t)n_base * 1024;

    f32x4 acc[4][4] = {};

    const int sm = (tid >> 3) & 7;                   // == (d>>3)&7 for d=it*256+tid
    auto STAGE = [&](int bf, int kt) {
        const int k0 = kt * 32;
#pragma unroll
        for (int it = 0; it < 2; ++it) {
            const int d = it * 256 + tid;
            const int l = d ^ sm;                    // involutive granule permutation
            const int r  = l >> 2;
            const int kc = k0 + (l & 3) * 8;
            unsigned short* dA = &lA[bf][(size_t)(it * 256 + wv * 64) * 8];
            unsigned short* dB = &lB[bf][(size_t)(it * 256 + wv * 64) * 8];
            gload16(A  + (size_t)r * 1024 + kc, dA);
            gload16(Wt + (size_t)r * 1024 + kc, dB);
        }
    };

    STAGE(0, 0);
    asm volatile("s_waitcnt vmcnt(0)" ::: "memory");
    __syncthreads();

    const int rm = (row >> 1) & 7;                   // == (s>>3)&7 for our read slots

    for (int kt = 0; kt < 32; ++kt) {
        const int cur = kt & 1;
        if (kt + 1 < 32) STAGE(cur ^ 1, kt + 1);

        bf16x8 a[4], b[4];
#pragma unroll
        for (int i = 0; i < 4; ++i) {
            const int s = ((wr * 64 + 16 * i + row) * 4 + quad) ^ rm;
            a[i] = ld8(BPc(&lA[cur][(size_t)s * 8]));
        }
#pragma unroll
        for (int j = 0; j < 4; ++j) {
            const int s = ((wc * 64 + 16 * j + row) * 4 + quad) ^ rm;
            b[j] = ld8(BPc(&lB[cur][(size_t)s * 8]));
        }
#pragma unroll
        for (int i = 0; i < 4; ++i)
#pragma unroll
            for (int j = 0; j < 4; ++j)
                acc[i][j] = MF(a[i], b[j], acc[i][j]);

        asm volatile("s_waitcnt vmcnt(0)" ::: "memory");
        __syncthreads();
    }

#pragma unroll
    for (int i = 0; i < 4; ++i)
#pragma unroll
        for (int j = 0; j < 4; ++j) {
            const int n = n_base + wc * 64 + 16 * j + row;
            const int nn = ((n & 1023) << 2) + (n >> 10);   // gate-interleaved
#pragma unroll
            for (int r = 0; r < 4; ++r) {
                const int m = m_base + wr * 64 + 16 * i + quad * 4 + r;
                float v = acc[i][j][r] + g_featb[(size_t)(m & 255) * G4 + n];
                BP(g_xg)[(size_t)m * G4 + nn] = __float2bfloat16(v);
            }
        }
}

// =============================================================
// Persistent LSTM chunk: 16 timesteps in ONE launch.
// Grid 256 blocks x 512 thr; block (jg 0..63, bh 0..3): j-cols [jg*16,+16),
// batches [bh*64,+64). Wave (mg,kh) = batch-16 group x kt-half (R5 layout).
// R6: block-PRIVATE state lives in REGISTERS across the chunk, immune to the
// per-step device-scope fence's L2 invalidation:
//   - c (2 f32/thread): loaded at chunk start, g_c stored once at chunk end
//   - own-h (2 f32/thread): frozen-case uses register, no re-read
//   - xg (2 ushort4/thread): gate-interleaved 8B load, PIPELINED — next
//     step's values fetched into regs BEFORE the barrier (g_xg immutable)
// Post-barrier cold path is now only the h A-frag loads.
// Group barrier: distributed arrive-flags per bh-group, R4/R5-proven.
// =============================================================
__global__ __launch_bounds__(512, 1) void lstm_chunk(
    const int* __restrict__ length,
    float* __restrict__ out,          // (T,B,H) f32 base (layer-1 writes)
    int c0, int layer)
{
    __shared__ unsigned short WL[64 * 1024];   // 128 KB fragment-ordered Whh
    __shared__ float gsum[64][65];             // 16.6 KB padded exchange
    __shared__ int   slen[64];                 // lengths for this block's batches
    __shared__ unsigned s_base;

    const int tid  = threadIdx.x;
    const int lane = tid & 63, wv = tid >> 6;
    const int row  = lane & 15, quad = lane >> 4;
    const int mg = wv >> 1, kh = wv & 1;       // batch-16 group, kt-half
    const int jg = blockIdx.x >> 2, bh = blockIdx.x & 3;
    const int j0 = jg * 16;
    const int bb0 = bh * 64;

    if (tid == 0)
        s_base = __hip_atomic_load(&g_arrive[bh][jg][0], __ATOMIC_RELAXED,
                                   __HIP_MEMORY_SCOPE_AGENT);
    if (tid < 64) slen[tid] = length[bb0 + tid];

    {   // ---- load Whh slice, fragment-ordered (once per chunk) ----
        const __hip_bfloat16* Whh = BPc(g_Whh) + (size_t)layer * G4 * 1024;
#pragma unroll
        for (int i = 0; i < 16; ++i) {
            const int G = tid + i * 512;                 // 0..8191 granules
            const int g = G >> 11, kt = (G >> 6) & 31, l = G & 63;
            *reinterpret_cast<bf16x8*>(&WL[(size_t)G * 8]) =
                ld8(Whh + (size_t)(g * 1024 + j0 + (l & 15)) * 1024
                        + kt * 32 + (l >> 4) * 8);
        }
    }

    // ---- per-thread element mapping (static across steps) ----
    int lbv[2], ljv[2];
    size_t idx[2], xoff[2];
    float c_reg[2], hprev[2];
#pragma unroll
    for (int it = 0; it < 2; ++it) {
        const int e = tid + it * 512;
        lbv[it] = e >> 4;  ljv[it] = e & 15;
        idx[it]  = (size_t)(bb0 + lbv[it]) * HH + j0 + ljv[it];
        xoff[it] = (size_t)(bb0 + lbv[it]) * G4 + (size_t)(j0 + ljv[it]) * 4;
        if (c0 == 0) { c_reg[it] = 0.0f; hprev[it] = 0.0f; }
        else {
            c_reg[it] = g_c[idx[it]];
            hprev[it] = bfu2f(g_h[(c0 + 1) & 1][idx[it]]);
        }
    }
    // prefetch xg for step 0
    ushort4 xq[2];
    xq[0] = *reinterpret_cast<const ushort4*>(g_xg + xoff[0]);
    xq[1] = *reinterpret_cast<const ushort4*>(g_xg + xoff[1]);

    __syncthreads();
    const unsigned base = s_base;

    for (int s = 0; s < CHT; ++s) {
        const int t = c0 + s;
        const __hip_bfloat16* h_in = (t > 0) ? BPc(g_h[(t + 1) & 1]) : nullptr;
        __hip_bfloat16* h_out = BP(g_h[t & 1]);

        f32x4 acc[4] = {};          // 4 gates, 16 batches, this kt-half
        if (h_in) {
            const __hip_bfloat16* ap =
                h_in + (size_t)(bb0 + mg * 16 + row) * HH + kh * 512 + quad * 8;
            const unsigned short* wl = &WL[(size_t)(kh * 1024 + lane) * 8];
#pragma unroll 8
            for (int kt = 0; kt < 16; ++kt) {
                bf16x8 af = ld8(ap + kt * 32);
                acc[0] = MF(af, *(const bf16x8*)(wl + (size_t)(0 * 16384 + kt * 512)), acc[0]);
                acc[1] = MF(af, *(const bf16x8*)(wl + (size_t)(1 * 16384 + kt * 512)), acc[1]);
                acc[2] = MF(af, *(const bf16x8*)(wl + (size_t)(2 * 16384 + kt * 512)), acc[2]);
                acc[3] = MF(af, *(const bf16x8*)(wl + (size_t)(3 * 16384 + kt * 512)), acc[3]);
            }
        }

        // ---- 2-phase kt-half reduction into gsum ----
        if (kh == 0) {
#pragma unroll
            for (int g = 0; g < 4; ++g)
#pragma unroll
                for (int r = 0; r < 4; ++r)
                    gsum[mg * 16 + quad * 4 + r][g * 16 + row] = acc[g][r];
        }
        __syncthreads();
        if (kh == 1) {
#pragma unroll
            for (int g = 0; g < 4; ++g)
#pragma unroll
                for (int r = 0; r < 4; ++r)
                    gsum[mg * 16 + quad * 4 + r][g * 16 + row] += acc[g][r];
        }
        __syncthreads();

        // ---- elementwise update: all private state in registers ----
#pragma unroll
        for (int it = 0; it < 2; ++it) {
            const int lb = lbv[it], lj = ljv[it];
            const float gi = gsum[lb][ 0 + lj] + bfu2f(xq[it].x);
            const float gf = gsum[lb][16 + lj] + bfu2f(xq[it].y);
            const float gg = gsum[lb][32 + lj] + bfu2f(xq[it].z);
            const float go = gsum[lb][48 + lj] + bfu2f(xq[it].w);
            float hv;
            if (t < slen[lb]) {
                c_reg[it] = fsig(gf) * c_reg[it] + fsig(gi) * ftanh(gg);
                hv = fsig(go) * ftanh(c_reg[it]);
            } else {
                hv = hprev[it];                    // frozen past seq end
            }
            hprev[it] = hv;
            const __hip_bfloat16 hb = __float2bfloat16(hv);
            h_out[idx[it]] = hb;
            if (layer == 0) BP(g_seq)[(size_t)t * BB * HH + idx[it]] = hb;
            else            out[(size_t)t * BB * HH + idx[it]] = hv;
        }

        if (s + 1 < CHT) {
            // prefetch next step's xg into regs BEFORE the fence (g_xg is
            // immutable during the chunk; registers immune to L2 inval)
            const unsigned short* xgn = g_xg + (size_t)(s + 1) * BB * G4;
            xq[0] = *reinterpret_cast<const ushort4*>(xgn + xoff[0]);
            xq[1] = *reinterpret_cast<const ushort4*>(xgn + xoff[1]);

            // ---- distributed group barrier (R4/R5-proven) ----
            __syncthreads();   // all elementwise writes issued+drained
            const unsigned want = base + (unsigned)s + 1u;
            if (tid == 0) {
                __threadfence();                           // release this step's writes
                __hip_atomic_store(&g_arrive[bh][jg][0], want,
                                   __ATOMIC_RELAXED, __HIP_MEMORY_SCOPE_AGENT);
            }
            if (wv == 0) {                                 // lane l watches block l
                unsigned v;
                do {
                    v = __hip_atomic_load(&g_arrive[bh][lane][0],
                                          __ATOMIC_RELAXED, __HIP_MEMORY_SCOPE_AGENT);
                    if (v < want) __builtin_amdgcn_s_sleep(2);
                } while (__any(v < want));
                __threadfence();                           // acquire side
            }
            __syncthreads();
        }
    }

    // ---- chunk end: persist c (and hv already in g_h) ----
    g_c[idx[0]] = c_reg[0];
    g_c[idx[1]] = c_reg[1];
}

// ---------------- small utility kernels ----------------
__global__ __launch_bounds__(256) void finish_layer(float* __restrict__ hn,
                                                    float* __restrict__ cn)
{
    const int i = blockIdx.x * 256 + threadIdx.x;
    hn[i] = (float)BPc(g_h[(TT - 1) & 1])[i];
    cn[i] = g_c[i];
}

// =============================================================
// host launcher — plain kernel launches ONLY (graph-capture safe)
// =============================================================
extern "C" void kernel_launch(void* const* d_in, const int* in_sizes, int n_in,
                              void* d_out, int out_size, void* d_ws, size_t ws_size,
                              hipStream_t stream)
{
    const float* x        = (const float*)d_in[0];  // (T,B,D)   f32
    const float* features = (const float*)d_in[1];  // (B,F)     f32
    const float* Wih      = (const float*)d_in[2];  // (L,4H,D)  f32
    const float* Whh      = (const float*)d_in[3];  // (L,4H,H)  f32
    const float* Wfh      = (const float*)d_in[4];  // (L,4H,F)  f32
    const float* bvec     = (const float*)d_in[5];  // (L,4H)    f32
    const int*   length   = (const int*)d_in[6];    // (B,)
    float* out = (float*)d_out;                     // f32 outputs

    const size_t nX = (size_t)TT * BB * DD;
    const size_t nW = (size_t)2 * G4 * 1024;
    const size_t nF = (size_t)BB * 1024;
    cvt_bf16<<<(int)(nX / 1024), 256, 0, stream>>>(0, x, nX);
    cvt_bf16<<<(int)(nW / 1024), 256, 0, stream>>>(1, Wih, nW);
    cvt_bf16<<<(int)(nW / 1024), 256, 0, stream>>>(2, Whh, nW);
    cvt_bf16<<<(int)(nW / 1024), 256, 0, stream>>>(3, Wfh, nW);
    cvt_bf16<<<(int)(nF / 1024), 256, 0, stream>>>(4, features, nF);

    float* out_hn = out + (size_t)TT * BB * HH;
    float* out_cn = out_hn + (size_t)2 * BB * HH;

    for (int l = 0; l < 2; ++l) {
        const size_t w_off = (size_t)l * G4 * 1024;

        gemm_featb<<<dim3(G4 / 64, BB / 128), 256, 0, stream>>>(
            w_off, bvec + (size_t)l * G4);

        for (int c0 = 0; c0 < TT; c0 += CHT) {
            // g_xg = g_seq[chunk] @ Wih[l]^T + g_featb  (bf16, gate-interleaved)
            gemm_xg<<<dim3(G4 / 128, CHT * BB / 128), 256, 0, stream>>>(
                (size_t)c0 * BB * DD, w_off);

            // 16 recurrent steps, one persistent launch with group barriers
            lstm_chunk<<<256, 512, 0, stream>>>(length, out, c0, l);
        }

        finish_layer<<<BB * HH / 256, 256, 0, stream>>>(
            out_hn + (size_t)l * BB * HH, out_cn + (size_t)l * BB * HH);
    }
}

// Round 8
// 2336.209 us; speedup vs baseline: 1.4632x; 1.3815x over previous
//
#include <hip/hip_runtime.h>
#include <hip/hip_bf16.h>

// ---------------- problem shape ----------------
#define TT 64
#define BB 256
#define DD 1024
#define HH 1024
#define G4 4096    // 4*H
#define CHT 16     // xg chunk length (timesteps); 4 chunks cover T=64

typedef __bf16 bf16x8 __attribute__((ext_vector_type(8)));
typedef float  f32x4  __attribute__((ext_vector_type(4)));
typedef unsigned short us8 __attribute__((ext_vector_type(8)));
typedef unsigned long long u64;

// ---------------- static device scratch (~119 MB, proven size) ----------------
__device__ unsigned short g_seq [(size_t)TT * BB * 1024];  // x (bf16) -> layer-1 h seq   32 MB
__device__ unsigned short g_Wih [(size_t)2 * G4 * 1024];   // 16 MB
__device__ unsigned short g_Whh [(size_t)2 * G4 * 1024];   // 16 MB
__device__ unsigned short g_Wfh [(size_t)2 * G4 * 1024];   // 16 MB
__device__ unsigned short g_feat[(size_t)BB * 1024];       // 0.5 MB
__device__ unsigned short g_xg  [(size_t)CHT * BB * G4];   // bf16 gates chunk (GATE-INTERLEAVED: [m][j*4+g])
// h state ping-pong, bf16 packed 4-per-u64 => 8B-aligned object so agent-scope
// atomic u64 loads / u32 stores compile cleanly (-Watomic-alignment).
__device__ u64            g_hq  [2][(size_t)BB * HH / 4];  // 1 MB
__device__ float          g_featb[(size_t)BB * G4];        // f32 feat@Wfh^T + b           4 MB
__device__ float          g_c   [(size_t)BB * HH];         // f32 cell state               1 MB

// distributed barrier flags: [bh group 0..3][jg block 0..63][64B pad].
// Monotonic epochs (never reset -> graph-replay safe); one cacheline per
// block -> parallel arrivals, parallel 64-lane polls (R4..R6-proven).
__device__ unsigned g_arrive[4][64][16];

__device__ __forceinline__ bf16x8 ld8(const __hip_bfloat16* p) {
    return *reinterpret_cast<const bf16x8*>(p);
}
__device__ __forceinline__ __hip_bfloat16* BP(unsigned short* p) {
    return reinterpret_cast<__hip_bfloat16*>(p);
}
__device__ __forceinline__ const __hip_bfloat16* BPc(const unsigned short* p) {
    return reinterpret_cast<const __hip_bfloat16*>(p);
}
__device__ __forceinline__ f32x4 MF(bf16x8 a, bf16x8 b, f32x4 c) {
    return __builtin_amdgcn_mfma_f32_16x16x32_bf16(a, b, c, 0, 0, 0);
}
__device__ __forceinline__ float fsig(float x) {
    return 1.0f / (1.0f + __expf(-x));
}
__device__ __forceinline__ float ftanh(float x) {   // clamped: exp never inf
    const float x2 = fminf(fmaxf(2.0f * x, -30.0f), 30.0f);
    const float e  = __expf(x2);
    return (e - 1.0f) / (e + 1.0f);
}
__device__ __forceinline__ float bfu2f(unsigned short u) {  // bf16 bits -> f32
    return __uint_as_float((unsigned)u << 16);
}
__device__ __forceinline__ unsigned short f2bu(float x) {   // f32 -> bf16 bits
    __hip_bfloat16 h = __float2bfloat16(x);
    return *reinterpret_cast<unsigned short*>(&h);
}

// direct global->LDS async copy, 16B per lane
typedef unsigned int u32_g __attribute__((address_space(1)));
typedef unsigned int u32_l __attribute__((address_space(3)));
__device__ __forceinline__ void gload16(const void* g, void* l) {
    __builtin_amdgcn_global_load_lds((const u32_g*)g, (u32_l*)l, 16, 0, 0);
}

// =============================================================
// f32 -> bf16 conversion into a selected device-global buffer.
// =============================================================
__global__ __launch_bounds__(256) void cvt_bf16(int which,
                                                const float* __restrict__ s,
                                                size_t n)
{
    size_t i = ((size_t)blockIdx.x * 256 + threadIdx.x) * 4;
    if (i >= n) return;
    unsigned short* d = (which == 0) ? g_seq
                      : (which == 1) ? g_Wih
                      : (which == 2) ? g_Whh
                      : (which == 3) ? g_Wfh : g_feat;
    float4 v = *reinterpret_cast<const float4*>(s + i);
    __hip_bfloat16* db = BP(d) + i;
    db[0] = __float2bfloat16(v.x);
    db[1] = __float2bfloat16(v.y);
    db[2] = __float2bfloat16(v.z);
    db[3] = __float2bfloat16(v.w);
}

// =============================================================
// Small-M featb GEMM: g_featb[256,4096] = feat @ Wfh[l]^T + b[l] (f32)
// =============================================================
__global__ __launch_bounds__(256) void gemm_featb(size_t w_off,
                                                  const float* __restrict__ bias)
{
    const int tid  = threadIdx.x;
    const int lane = tid & 63, wid = tid >> 6;
    const int row  = lane & 15, quad = lane >> 4;
    const int m_base = blockIdx.y * 128 + (wid >> 1) * 64;
    const int n_base = blockIdx.x * 64  + (wid & 1) * 32;

    const __hip_bfloat16* A = BPc(g_feat);
    const __hip_bfloat16* W = BPc(g_Wfh) + w_off;

    f32x4 acc[4][2] = {};
    const __hip_bfloat16* Ap = A + (size_t)(m_base + row) * 1024 + quad * 8;
    const __hip_bfloat16* Wp = W + (size_t)(n_base + row) * 1024 + quad * 8;

    for (int k0 = 0; k0 < 1024; k0 += 32) {
        bf16x8 a[4], b[2];
#pragma unroll
        for (int i = 0; i < 4; ++i) a[i] = ld8(Ap + (size_t)(16 * i) * 1024 + k0);
#pragma unroll
        for (int j = 0; j < 2; ++j) b[j] = ld8(Wp + (size_t)(16 * j) * 1024 + k0);
#pragma unroll
        for (int i = 0; i < 4; ++i)
#pragma unroll
            for (int j = 0; j < 2; ++j)
                acc[i][j] = MF(a[i], b[j], acc[i][j]);
    }
#pragma unroll
    for (int i = 0; i < 4; ++i)
#pragma unroll
        for (int j = 0; j < 2; ++j) {
            const int n = n_base + 16 * j + row;
#pragma unroll
            for (int r = 0; r < 4; ++r) {
                const int m = m_base + 16 * i + quad * 4 + r;
                g_featb[(size_t)m * G4 + n] = acc[i][j][r] + bias[n];
            }
        }
}

// =============================================================
// xg GEMM (chunk): C[4096,4096] = g_seq[chunk] @ Wih[l]^T  (+featb, ->bf16)
// 128x128 tile, BK=32, double-buffered LDS via global_load_lds(16B).
// Involutive both-sides LDS swizzle (R4-verified) + XCD block swizzle.
// Epilogue writes GATE-INTERLEAVED g_xg[m][(n&1023)*4 + (n>>10)].
// =============================================================
__global__ __launch_bounds__(256) void gemm_xg(size_t seq_off, size_t w_off)
{
    __shared__ unsigned short lA[2][128 * 32];
    __shared__ unsigned short lB[2][128 * 32];

    const int tid  = threadIdx.x;
    const int lane = tid & 63, wv = tid >> 6;
    const int row  = lane & 15, quad = lane >> 4;
    const int wr = wv >> 1, wc = wv & 1;

    // XCD swizzle: consecutive tiles land on the same XCD's L2
    const int flat = blockIdx.y * gridDim.x + blockIdx.x;
    const int cpx  = (gridDim.x * gridDim.y) >> 3;
    const int swz  = (flat & 7) * cpx + (flat >> 3);
    const int m_base = (swz / gridDim.x) * 128;
    const int n_base = (swz % gridDim.x) * 128;

    const __hip_bfloat16* A  = BPc(g_seq) + seq_off + (size_t)m_base * 1024;
    const __hip_bfloat16* Wt = BPc(g_Wih) + w_off   + (size_t)n_base * 1024;

    f32x4 acc[4][4] = {};

    const int sm = (tid >> 3) & 7;                   // == (d>>3)&7 for d=it*256+tid
    auto STAGE = [&](int bf, int kt) {
        const int k0 = kt * 32;
#pragma unroll
        for (int it = 0; it < 2; ++it) {
            const int d = it * 256 + tid;
            const int l = d ^ sm;                    // involutive granule permutation
            const int r  = l >> 2;
            const int kc = k0 + (l & 3) * 8;
            unsigned short* dA = &lA[bf][(size_t)(it * 256 + wv * 64) * 8];
            unsigned short* dB = &lB[bf][(size_t)(it * 256 + wv * 64) * 8];
            gload16(A  + (size_t)r * 1024 + kc, dA);
            gload16(Wt + (size_t)r * 1024 + kc, dB);
        }
    };

    STAGE(0, 0);
    asm volatile("s_waitcnt vmcnt(0)" ::: "memory");
    __syncthreads();

    const int rm = (row >> 1) & 7;                   // == (s>>3)&7 for our read slots

    for (int kt = 0; kt < 32; ++kt) {
        const int cur = kt & 1;
        if (kt + 1 < 32) STAGE(cur ^ 1, kt + 1);

        bf16x8 a[4], b[4];
#pragma unroll
        for (int i = 0; i < 4; ++i) {
            const int s = ((wr * 64 + 16 * i + row) * 4 + quad) ^ rm;
            a[i] = ld8(BPc(&lA[cur][(size_t)s * 8]));
        }
#pragma unroll
        for (int j = 0; j < 4; ++j) {
            const int s = ((wc * 64 + 16 * j + row) * 4 + quad) ^ rm;
            b[j] = ld8(BPc(&lB[cur][(size_t)s * 8]));
        }
#pragma unroll
        for (int i = 0; i < 4; ++i)
#pragma unroll
            for (int j = 0; j < 4; ++j)
                acc[i][j] = MF(a[i], b[j], acc[i][j]);

        asm volatile("s_waitcnt vmcnt(0)" ::: "memory");
        __syncthreads();
    }

#pragma unroll
    for (int i = 0; i < 4; ++i)
#pragma unroll
        for (int j = 0; j < 4; ++j) {
            const int n = n_base + wc * 64 + 16 * j + row;
            const int nn = ((n & 1023) << 2) + (n >> 10);   // gate-interleaved
#pragma unroll
            for (int r = 0; r < 4; ++r) {
                const int m = m_base + wr * 64 + 16 * i + quad * 4 + r;
                float v = acc[i][j][r] + g_featb[(size_t)(m & 255) * G4 + n];
                BP(g_xg)[(size_t)m * G4 + nn] = __float2bfloat16(v);
            }
        }
}

// =============================================================
// Persistent LSTM chunk: 16 timesteps in ONE launch.
// Grid 256 blocks x 512 thr; block (jg 0..63, bh 0..3): j-cols [jg*16,+16),
// batches [bh*64,+64). Wave (mg,kh) = batch-16 group x kt-half.
// R8 (= R7 design, compile-fixed): NO cache-wide fences. The only
// intra-kernel cross-block data is h and the flags; both use agent-scope
// relaxed atomics (coherence-point ops, bypassing the non-coherent per-XCD
// L2 — the m20-verified mechanism). h lives in the 8B-aligned u64 buffer
// g_hq so atomics compile (-Watomic-alignment was R7's failure).
//   release: __syncthreads() drains vmcnt(0) => all h stores acked at the
//            coherence point; THEN tid0 stores its flag (relaxed atomic).
//   acquire: poll flags (relaxed atomic loads); h loads are themselves
//            coherence-point reads, so no L2 invalidate is needed.
// This deletes buffer_wbl2/buffer_inv (R6: run 15x/chunk on all 256 blocks)
// from the inner loop.
// Elementwise: j-PAIR per thread; xg one 16B load; h-store one packed u32
// agent atomic; out float2. All 16 h A-frags loaded up-front (32 indep u64
// agent loads, fully unrolled) before the MFMA loop.
// =============================================================
__global__ __launch_bounds__(512, 1) void lstm_chunk(
    const int* __restrict__ length,
    float* __restrict__ out,          // (T,B,H) f32 base (layer-1 writes)
    int c0, int layer)
{
    __shared__ unsigned short WL[64 * 1024];   // 128 KB fragment-ordered Whh
    __shared__ float gsum[64][65];             // 16.6 KB padded exchange
    __shared__ int   slen[64];                 // lengths for this block's batches
    __shared__ unsigned s_base;

    const int tid  = threadIdx.x;
    const int lane = tid & 63, wv = tid >> 6;
    const int row  = lane & 15, quad = lane >> 4;
    const int mg = wv >> 1, kh = wv & 1;       // batch-16 group, kt-half
    const int jg = blockIdx.x >> 2, bh = blockIdx.x & 3;
    const int j0 = jg * 16;
    const int bb0 = bh * 64;

    if (tid == 0)
        s_base = __hip_atomic_load(&g_arrive[bh][jg][0], __ATOMIC_RELAXED,
                                   __HIP_MEMORY_SCOPE_AGENT);
    if (tid < 64) slen[tid] = length[bb0 + tid];

    {   // ---- load Whh slice, fragment-ordered (once per chunk) ----
        const __hip_bfloat16* Whh = BPc(g_Whh) + (size_t)layer * G4 * 1024;
#pragma unroll
        for (int i = 0; i < 16; ++i) {
            const int G = tid + i * 512;                 // 0..8191 granules
            const int g = G >> 11, kt = (G >> 6) & 31, l = G & 63;
            *reinterpret_cast<bf16x8*>(&WL[(size_t)G * 8]) =
                ld8(Whh + (size_t)(g * 1024 + j0 + (l & 15)) * 1024
                        + kt * 32 + (l >> 4) * 8);
        }
    }

    // ---- per-thread elementwise mapping: one j-PAIR per thread ----
    const int lb  = tid >> 3;                  // batch row 0..63
    const int lj  = (tid & 7) * 2;             // col pair 0,2,..,14
    const size_t idx  = (size_t)(bb0 + lb) * HH + j0 + lj;            // even
    const size_t xoff = (size_t)(bb0 + lb) * G4 + (size_t)(j0 + lj) * 4;  // 16B-aligned
    float c_r0, c_r1, hp0, hp1;
    if (c0 == 0) { c_r0 = c_r1 = hp0 = hp1 = 0.0f; }
    else {
        const float2 cc = *reinterpret_cast<const float2*>(&g_c[idx]);
        c_r0 = cc.x;  c_r1 = cc.y;
        const unsigned hu =
            reinterpret_cast<const unsigned*>(g_hq[(c0 + 1) & 1])[idx >> 1];
        hp0 = bfu2f((unsigned short)(hu & 0xffffu));
        hp1 = bfu2f((unsigned short)(hu >> 16));
    }
    // prefetch xg for step 0 (gate-interleaved: 8 ushorts = both cols x 4 gates)
    us8 xq = *reinterpret_cast<const us8*>(g_xg + xoff);

    __syncthreads();
    const unsigned base = s_base;

    for (int s = 0; s < CHT; ++s) {
        const int t = c0 + s;

        f32x4 acc[4] = {};          // 4 gates, 16 batches, this kt-half
        if (t > 0) {
            // h A-frags: agent-coherent u64 loads from the u64-typed buffer
            const u64* hq = g_hq[(t + 1) & 1] +
                (((size_t)(bb0 + mg * 16 + row) * HH + kh * 512 + quad * 8) >> 2);
            union { u64 q[2]; bf16x8 v; } af[16];
#pragma unroll
            for (int kt = 0; kt < 16; ++kt) {      // 32 independent coherent loads
                af[kt].q[0] = __hip_atomic_load(hq + kt * 8,     __ATOMIC_RELAXED,
                                                __HIP_MEMORY_SCOPE_AGENT);
                af[kt].q[1] = __hip_atomic_load(hq + kt * 8 + 1, __ATOMIC_RELAXED,
                                                __HIP_MEMORY_SCOPE_AGENT);
            }
            const unsigned short* wl = &WL[(size_t)(kh * 1024 + lane) * 8];
#pragma unroll
            for (int kt = 0; kt < 16; ++kt) {
                acc[0] = MF(af[kt].v, *(const bf16x8*)(wl + (size_t)(0 * 16384 + kt * 512)), acc[0]);
                acc[1] = MF(af[kt].v, *(const bf16x8*)(wl + (size_t)(1 * 16384 + kt * 512)), acc[1]);
                acc[2] = MF(af[kt].v, *(const bf16x8*)(wl + (size_t)(2 * 16384 + kt * 512)), acc[2]);
                acc[3] = MF(af[kt].v, *(const bf16x8*)(wl + (size_t)(3 * 16384 + kt * 512)), acc[3]);
            }
        }

        // ---- 2-phase kt-half reduction into gsum ----
        if (kh == 0) {
#pragma unroll
            for (int g = 0; g < 4; ++g)
#pragma unroll
                for (int r = 0; r < 4; ++r)
                    gsum[mg * 16 + quad * 4 + r][g * 16 + row] = acc[g][r];
        }
        __syncthreads();
        if (kh == 1) {
#pragma unroll
            for (int g = 0; g < 4; ++g)
#pragma unroll
                for (int r = 0; r < 4; ++r)
                    gsum[mg * 16 + quad * 4 + r][g * 16 + row] += acc[g][r];
        }
        __syncthreads();

        // ---- elementwise update: j-pair per thread, private state in regs ----
        {
            const float gi0 = gsum[lb][ 0 + lj]     + bfu2f(xq[0]);
            const float gf0 = gsum[lb][16 + lj]     + bfu2f(xq[1]);
            const float gg0 = gsum[lb][32 + lj]     + bfu2f(xq[2]);
            const float go0 = gsum[lb][48 + lj]     + bfu2f(xq[3]);
            const float gi1 = gsum[lb][ 0 + lj + 1] + bfu2f(xq[4]);
            const float gf1 = gsum[lb][16 + lj + 1] + bfu2f(xq[5]);
            const float gg1 = gsum[lb][32 + lj + 1] + bfu2f(xq[6]);
            const float go1 = gsum[lb][48 + lj + 1] + bfu2f(xq[7]);
            float hv0, hv1;
            if (t < slen[lb]) {
                c_r0 = fsig(gf0) * c_r0 + fsig(gi0) * ftanh(gg0);
                c_r1 = fsig(gf1) * c_r1 + fsig(gi1) * ftanh(gg1);
                hv0 = fsig(go0) * ftanh(c_r0);
                hv1 = fsig(go1) * ftanh(c_r1);
            } else {
                hv0 = hp0;  hv1 = hp1;             // frozen past seq end
            }
            hp0 = hv0;  hp1 = hv1;
            const unsigned hb = (unsigned)f2bu(hv0) | ((unsigned)f2bu(hv1) << 16);
            // h: agent-coherent store (the ONLY intra-kernel cross-block data)
            __hip_atomic_store(
                reinterpret_cast<unsigned*>(g_hq[t & 1]) + (idx >> 1), hb,
                __ATOMIC_RELAXED, __HIP_MEMORY_SCOPE_AGENT);
            if (layer == 0) {
                *reinterpret_cast<unsigned*>(&g_seq[(size_t)t * BB * HH + idx]) = hb;
            } else {
                float2 o;  o.x = hv0;  o.y = hv1;
                *reinterpret_cast<float2*>(&out[(size_t)t * BB * HH + idx]) = o;
            }
        }

        if (s + 1 < CHT) {
            // prefetch next step's xg (g_xg immutable during the chunk)
            xq = *reinterpret_cast<const us8*>(
                g_xg + (size_t)(s + 1) * BB * G4 + xoff);

            // ---- group barrier: release = syncthreads-drain + flag store ----
            __syncthreads();   // s_waitcnt vmcnt(0): all h stores acked at IF
            const unsigned want = base + (unsigned)s + 1u;
            if (tid == 0)
                __hip_atomic_store(&g_arrive[bh][jg][0], want,
                                   __ATOMIC_RELAXED, __HIP_MEMORY_SCOPE_AGENT);
            if (wv == 0) {                                 // lane l watches block l
                unsigned v;
                do {
                    v = __hip_atomic_load(&g_arrive[bh][lane][0],
                                          __ATOMIC_RELAXED, __HIP_MEMORY_SCOPE_AGENT);
                    if (v < want) __builtin_amdgcn_s_sleep(4);
                } while (__any(v < want));
            }
            __syncthreads();
        }
    }

    // ---- chunk end: persist c ----
    float2 cc;  cc.x = c_r0;  cc.y = c_r1;
    *reinterpret_cast<float2*>(&g_c[idx]) = cc;
}

// ---------------- small utility kernels ----------------
__global__ __launch_bounds__(256) void finish_layer(float* __restrict__ hn,
                                                    float* __restrict__ cn)
{
    const int i = blockIdx.x * 256 + threadIdx.x;
    const unsigned short* hfin =
        reinterpret_cast<const unsigned short*>(g_hq[(TT - 1) & 1]);
    hn[i] = bfu2f(hfin[i]);
    cn[i] = g_c[i];
}

// =============================================================
// host launcher — plain kernel launches ONLY (graph-capture safe)
// =============================================================
extern "C" void kernel_launch(void* const* d_in, const int* in_sizes, int n_in,
                              void* d_out, int out_size, void* d_ws, size_t ws_size,
                              hipStream_t stream)
{
    const float* x        = (const float*)d_in[0];  // (T,B,D)   f32
    const float* features = (const float*)d_in[1];  // (B,F)     f32
    const float* Wih      = (const float*)d_in[2];  // (L,4H,D)  f32
    const float* Whh      = (const float*)d_in[3];  // (L,4H,H)  f32
    const float* Wfh      = (const float*)d_in[4];  // (L,4H,F)  f32
    const float* bvec     = (const float*)d_in[5];  // (L,4H)    f32
    const int*   length   = (const int*)d_in[6];    // (B,)
    float* out = (float*)d_out;                     // f32 outputs

    const size_t nX = (size_t)TT * BB * DD;
    const size_t nW = (size_t)2 * G4 * 1024;
    const size_t nF = (size_t)BB * 1024;
    cvt_bf16<<<(int)(nX / 1024), 256, 0, stream>>>(0, x, nX);
    cvt_bf16<<<(int)(nW / 1024), 256, 0, stream>>>(1, Wih, nW);
    cvt_bf16<<<(int)(nW / 1024), 256, 0, stream>>>(2, Whh, nW);
    cvt_bf16<<<(int)(nW / 1024), 256, 0, stream>>>(3, Wfh, nW);
    cvt_bf16<<<(int)(nF / 1024), 256, 0, stream>>>(4, features, nF);

    float* out_hn = out + (size_t)TT * BB * HH;
    float* out_cn = out_hn + (size_t)2 * BB * HH;

    for (int l = 0; l < 2; ++l) {
        const size_t w_off = (size_t)l * G4 * 1024;

        gemm_featb<<<dim3(G4 / 64, BB / 128), 256, 0, stream>>>(
            w_off, bvec + (size_t)l * G4);

        for (int c0 = 0; c0 < TT; c0 += CHT) {
            // g_xg = g_seq[chunk] @ Wih[l]^T + g_featb  (bf16, gate-interleaved)
            gemm_xg<<<dim3(G4 / 128, CHT * BB / 128), 256, 0, stream>>>(
                (size_t)c0 * BB * DD, w_off);

            // 16 recurrent steps, one persistent launch with group barriers
            lstm_chunk<<<256, 512, 0, stream>>>(length, out, c0, l);
        }

        finish_layer<<<BB * HH / 256, 256, 0, stream>>>(
            out_hn + (size_t)l * BB * HH, out_cn + (size_t)l * BB * HH);
    }
}

// Round 9
// 1828.609 us; speedup vs baseline: 1.8694x; 1.2776x over previous
//
#include <hip/hip_runtime.h>
#include <hip/hip_bf16.h>

// ---------------- problem shape ----------------
#define TT 64
#define BB 256
#define DD 1024
#define HH 1024
#define G4 4096    // 4*H
#define CHT 16     // xg chunk length (timesteps); 4 chunks cover T=64

typedef __bf16 bf16x8 __attribute__((ext_vector_type(8)));
typedef float  f32x4  __attribute__((ext_vector_type(4)));
typedef unsigned short us8 __attribute__((ext_vector_type(8)));
typedef unsigned long long u64;

// ---------------- static device scratch (~127 MB) ----------------
__device__ unsigned short g_seq [(size_t)TT * BB * 1024];  // x (bf16) -> layer-1 h seq   32 MB
__device__ unsigned short g_Wih [(size_t)2 * G4 * 1024];   // 16 MB
__device__ unsigned short g_Whh [(size_t)2 * G4 * 1024];   // 16 MB
__device__ unsigned short g_Wfh [(size_t)2 * G4 * 1024];   // 16 MB
__device__ unsigned short g_feat[(size_t)BB * 1024];       // 0.5 MB
__device__ unsigned short g_xg  [(size_t)CHT * BB * G4];   // bf16 gates chunk (GATE-INTERLEAVED: [m][j*4+g])
// R9: h rotates through CHT per-step buffers (8 MB). Step s WRITES buffer
// CHT-1-s (agent-atomic, write-through to coherence point) and READS buffer
// CHT-s (s=0: buffer 0 = previous kernel's last write) with PLAIN CACHED
// loads: within a chunk each buffer is read exactly once, strictly after its
// unique write, and never touched earlier in the kernel -> no stale L2 line
// can exist; kernel-launch acquire invalidates between chunks. Reverse order
// makes ascending HW prefetch spill only into already-consumed buffers.
__device__ u64            g_hb  [CHT][(size_t)BB * HH / 4];
__device__ float          g_featb[(size_t)BB * G4];        // f32 feat@Wfh^T+b, nn-layout  4 MB
__device__ float          g_c   [(size_t)BB * HH];         // f32 cell state               1 MB

// distributed barrier flags: [bh group 0..3][jg block 0..63][64B pad].
// Monotonic epochs (never reset -> graph-replay safe); one cacheline per
// block -> parallel arrivals, parallel 64-lane polls (R4..R8-proven).
__device__ unsigned g_arrive[4][64][16];

__device__ __forceinline__ bf16x8 ld8(const __hip_bfloat16* p) {
    return *reinterpret_cast<const bf16x8*>(p);
}
__device__ __forceinline__ __hip_bfloat16* BP(unsigned short* p) {
    return reinterpret_cast<__hip_bfloat16*>(p);
}
__device__ __forceinline__ const __hip_bfloat16* BPc(const unsigned short* p) {
    return reinterpret_cast<const __hip_bfloat16*>(p);
}
__device__ __forceinline__ f32x4 MF(bf16x8 a, bf16x8 b, f32x4 c) {
    return __builtin_amdgcn_mfma_f32_16x16x32_bf16(a, b, c, 0, 0, 0);
}
__device__ __forceinline__ float fsig(float x) {
    return 1.0f / (1.0f + __expf(-x));
}
__device__ __forceinline__ float ftanh(float x) {   // clamped: exp never inf
    const float x2 = fminf(fmaxf(2.0f * x, -30.0f), 30.0f);
    const float e  = __expf(x2);
    return (e - 1.0f) / (e + 1.0f);
}
__device__ __forceinline__ float bfu2f(unsigned short u) {  // bf16 bits -> f32
    return __uint_as_float((unsigned)u << 16);
}
__device__ __forceinline__ unsigned short f2bu(float x) {   // f32 -> bf16 bits
    __hip_bfloat16 h = __float2bfloat16(x);
    return *reinterpret_cast<unsigned short*>(&h);
}

// direct global->LDS async copy, 16B per lane
typedef unsigned int u32_g __attribute__((address_space(1)));
typedef unsigned int u32_l __attribute__((address_space(3)));
__device__ __forceinline__ void gload16(const void* g, void* l) {
    __builtin_amdgcn_global_load_lds((const u32_g*)g, (u32_l*)l, 16, 0, 0);
}

// =============================================================
// f32 -> bf16 conversion into a selected device-global buffer.
// =============================================================
__global__ __launch_bounds__(256) void cvt_bf16(int which,
                                                const float* __restrict__ s,
                                                size_t n)
{
    size_t i = ((size_t)blockIdx.x * 256 + threadIdx.x) * 4;
    if (i >= n) return;
    unsigned short* d = (which == 0) ? g_seq
                      : (which == 1) ? g_Wih
                      : (which == 2) ? g_Whh
                      : (which == 3) ? g_Wfh : g_feat;
    float4 v = *reinterpret_cast<const float4*>(s + i);
    __hip_bfloat16* db = BP(d) + i;
    db[0] = __float2bfloat16(v.x);
    db[1] = __float2bfloat16(v.y);
    db[2] = __float2bfloat16(v.z);
    db[3] = __float2bfloat16(v.w);
}

// =============================================================
// Small-M featb GEMM: g_featb[256, nn(4096)] = feat @ Wfh[l]^T + b[l] (f32)
// R9: stores in GATE-INTERLEAVED nn-layout (nn = (n&1023)*4 + n>>10) so
// gemm_xg's epilogue read is contiguous.
// =============================================================
__global__ __launch_bounds__(256) void gemm_featb(size_t w_off,
                                                  const float* __restrict__ bias)
{
    const int tid  = threadIdx.x;
    const int lane = tid & 63, wid = tid >> 6;
    const int row  = lane & 15, quad = lane >> 4;
    const int m_base = blockIdx.y * 128 + (wid >> 1) * 64;
    const int n_base = blockIdx.x * 64  + (wid & 1) * 32;

    const __hip_bfloat16* A = BPc(g_feat);
    const __hip_bfloat16* W = BPc(g_Wfh) + w_off;

    f32x4 acc[4][2] = {};
    const __hip_bfloat16* Ap = A + (size_t)(m_base + row) * 1024 + quad * 8;
    const __hip_bfloat16* Wp = W + (size_t)(n_base + row) * 1024 + quad * 8;

    for (int k0 = 0; k0 < 1024; k0 += 32) {
        bf16x8 a[4], b[2];
#pragma unroll
        for (int i = 0; i < 4; ++i) a[i] = ld8(Ap + (size_t)(16 * i) * 1024 + k0);
#pragma unroll
        for (int j = 0; j < 2; ++j) b[j] = ld8(Wp + (size_t)(16 * j) * 1024 + k0);
#pragma unroll
        for (int i = 0; i < 4; ++i)
#pragma unroll
            for (int j = 0; j < 2; ++j)
                acc[i][j] = MF(a[i], b[j], acc[i][j]);
    }
#pragma unroll
    for (int i = 0; i < 4; ++i)
#pragma unroll
        for (int j = 0; j < 2; ++j) {
            const int n = n_base + 16 * j + row;
            const int nn = ((n & 1023) << 2) + (n >> 10);   // gate-interleaved
#pragma unroll
            for (int r = 0; r < 4; ++r) {
                const int m = m_base + 16 * i + quad * 4 + r;
                g_featb[(size_t)m * G4 + nn] = acc[i][j][r] + bias[n];
            }
        }
}

// =============================================================
// xg GEMM (chunk): C = g_seq[chunk] @ Wih[l]^T (+featb, ->bf16, nn-layout)
// 128x128 tile, BK=32, double-buffered LDS via global_load_lds(16B),
// involutive both-sides LDS swizzle (R4-verified) + XCD block swizzle.
// R9: GATE-MIXED B tile — LDS B-row p holds Wih row (p&3)*1024 + cb + (p>>2)
// (cb = 32-col base). Then output nn = cb*4 + p: adjacent lanes store
// ADJACENT ushorts (32B contiguous segments) instead of stride-4 scatter,
// and the featb read (nn-layout) is contiguous too.
// =============================================================
__global__ __launch_bounds__(256) void gemm_xg(size_t seq_off, size_t w_off)
{
    __shared__ unsigned short lA[2][128 * 32];
    __shared__ unsigned short lB[2][128 * 32];

    const int tid  = threadIdx.x;
    const int lane = tid & 63, wv = tid >> 6;
    const int row  = lane & 15, quad = lane >> 4;
    const int wr = wv >> 1, wc = wv & 1;

    // XCD swizzle: consecutive tiles land on the same XCD's L2
    const int flat = blockIdx.y * gridDim.x + blockIdx.x;
    const int cpx  = (gridDim.x * gridDim.y) >> 3;
    const int swz  = (flat & 7) * cpx + (flat >> 3);
    const int m_base = (swz / gridDim.x) * 128;
    const int cb     = (swz % gridDim.x) * 32;     // 32 true-column base

    const __hip_bfloat16* A  = BPc(g_seq) + seq_off + (size_t)m_base * 1024;
    const __hip_bfloat16* Wt = BPc(g_Wih) + w_off;

    f32x4 acc[4][4] = {};

    const int sm = (tid >> 3) & 7;                   // == (d>>3)&7 for d=it*256+tid
    auto STAGE = [&](int bf, int kt) {
        const int k0 = kt * 32;
#pragma unroll
        for (int it = 0; it < 2; ++it) {
            const int d = it * 256 + tid;
            const int l = d ^ sm;                    // involutive granule permutation
            const int r  = l >> 2;                   // LDS row p (A: m-row)
            const int kc = k0 + (l & 3) * 8;
            unsigned short* dA = &lA[bf][(size_t)(it * 256 + wv * 64) * 8];
            unsigned short* dB = &lB[bf][(size_t)(it * 256 + wv * 64) * 8];
            gload16(A + (size_t)r * 1024 + kc, dA);
            // gate-mixed B row: p -> Wih row (p&3)*1024 + cb + (p>>2)
            const int nrow = ((r & 3) << 10) + cb + (r >> 2);
            gload16(Wt + (size_t)nrow * 1024 + kc, dB);
        }
    };

    STAGE(0, 0);
    asm volatile("s_waitcnt vmcnt(0)" ::: "memory");
    __syncthreads();

    const int rm = (row >> 1) & 7;                   // == (s>>3)&7 for our read slots

    for (int kt = 0; kt < 32; ++kt) {
        const int cur = kt & 1;
        if (kt + 1 < 32) STAGE(cur ^ 1, kt + 1);

        bf16x8 a[4], b[4];
#pragma unroll
        for (int i = 0; i < 4; ++i) {
            const int s = ((wr * 64 + 16 * i + row) * 4 + quad) ^ rm;
            a[i] = ld8(BPc(&lA[cur][(size_t)s * 8]));
        }
#pragma unroll
        for (int j = 0; j < 4; ++j) {
            const int s = ((wc * 64 + 16 * j + row) * 4 + quad) ^ rm;
            b[j] = ld8(BPc(&lB[cur][(size_t)s * 8]));
        }
#pragma unroll
        for (int i = 0; i < 4; ++i)
#pragma unroll
            for (int j = 0; j < 4; ++j)
                acc[i][j] = MF(a[i], b[j], acc[i][j]);

        asm volatile("s_waitcnt vmcnt(0)" ::: "memory");
        __syncthreads();
    }

#pragma unroll
    for (int i = 0; i < 4; ++i)
#pragma unroll
        for (int j = 0; j < 4; ++j) {
            const int p  = wc * 64 + 16 * j + row;     // tile-local n position
            const int nn = cb * 4 + p;                 // contiguous output index
#pragma unroll
            for (int r = 0; r < 4; ++r) {
                const int m = m_base + wr * 64 + 16 * i + quad * 4 + r;
                float v = acc[i][j][r] + g_featb[(size_t)(m & 255) * G4 + nn];
                BP(g_xg)[(size_t)m * G4 + nn] = __float2bfloat16(v);
            }
        }
}

// =============================================================
// Persistent LSTM chunk: 16 timesteps in ONE launch.
// Grid 256 blocks x 512 thr; block (jg 0..63, bh 0..3): j-cols [jg*16,+16),
// batches [bh*64,+64). Wave (mg,kh) = batch-16 group x kt-half.
// R9: h reads are PLAIN CACHED loads from the rotating per-step buffer
// (see g_hb comment) — per-XCD L2 absorbs the 64x intra-group read
// redundancy that R8 paid at the coherence point (32 MB/step of bypass
// reads). h writes remain agent-atomic u32 (write-through). Barrier
// unchanged (R8-proven: syncthreads-drain release + flag store + poll).
// =============================================================
__global__ __launch_bounds__(512, 1) void lstm_chunk(
    const int* __restrict__ length,
    float* __restrict__ out,          // (T,B,H) f32 base (layer-1 writes)
    int c0, int layer)
{
    __shared__ unsigned short WL[64 * 1024];   // 128 KB fragment-ordered Whh
    __shared__ float gsum[64][65];             // 16.6 KB padded exchange
    __shared__ int   slen[64];                 // lengths for this block's batches
    __shared__ unsigned s_base;

    const int tid  = threadIdx.x;
    const int lane = tid & 63, wv = tid >> 6;
    const int row  = lane & 15, quad = lane >> 4;
    const int mg = wv >> 1, kh = wv & 1;       // batch-16 group, kt-half
    const int jg = blockIdx.x >> 2, bh = blockIdx.x & 3;
    const int j0 = jg * 16;
    const int bb0 = bh * 64;

    if (tid == 0)
        s_base = __hip_atomic_load(&g_arrive[bh][jg][0], __ATOMIC_RELAXED,
                                   __HIP_MEMORY_SCOPE_AGENT);
    if (tid < 64) slen[tid] = length[bb0 + tid];

    {   // ---- load Whh slice, fragment-ordered (once per chunk) ----
        const __hip_bfloat16* Whh = BPc(g_Whh) + (size_t)layer * G4 * 1024;
#pragma unroll
        for (int i = 0; i < 16; ++i) {
            const int G = tid + i * 512;                 // 0..8191 granules
            const int g = G >> 11, kt = (G >> 6) & 31, l = G & 63;
            *reinterpret_cast<bf16x8*>(&WL[(size_t)G * 8]) =
                ld8(Whh + (size_t)(g * 1024 + j0 + (l & 15)) * 1024
                        + kt * 32 + (l >> 4) * 8);
        }
    }

    // ---- per-thread elementwise mapping: one j-PAIR per thread ----
    const int lb  = tid >> 3;                  // batch row 0..63
    const int lj  = (tid & 7) * 2;             // col pair 0,2,..,14
    const size_t idx  = (size_t)(bb0 + lb) * HH + j0 + lj;            // even
    const size_t xoff = (size_t)(bb0 + lb) * G4 + (size_t)(j0 + lj) * 4;  // 16B-aligned
    float c_r0, c_r1, hp0, hp1;
    if (c0 == 0) { c_r0 = c_r1 = hp0 = hp1 = 0.0f; }
    else {
        const float2 cc = *reinterpret_cast<const float2*>(&g_c[idx]);
        c_r0 = cc.x;  c_r1 = cc.y;
        // previous kernel's last write landed in buffer 0
        const unsigned hu = reinterpret_cast<const unsigned*>(g_hb[0])[idx >> 1];
        hp0 = bfu2f((unsigned short)(hu & 0xffffu));
        hp1 = bfu2f((unsigned short)(hu >> 16));
    }
    // prefetch xg for step 0 (gate-interleaved: 8 ushorts = both cols x 4 gates)
    us8 xq = *reinterpret_cast<const us8*>(g_xg + xoff);

    __syncthreads();
    const unsigned base = s_base;

    for (int s = 0; s < CHT; ++s) {
        const int t = c0 + s;
        const int wb = CHT - 1 - s;                     // write buffer
        const int rb = (s == 0) ? 0 : (CHT - s);        // read buffer (= prev write)

        f32x4 acc[4] = {};          // 4 gates, 16 batches, this kt-half
        if (t > 0) {
            // h A-frags: PLAIN cached 16B loads (L2-served; see g_hb comment)
            const __hip_bfloat16* hp = reinterpret_cast<const __hip_bfloat16*>(g_hb[rb])
                + (size_t)(bb0 + mg * 16 + row) * HH + kh * 512 + quad * 8;
            bf16x8 af[16];
#pragma unroll
            for (int kt = 0; kt < 16; ++kt)             // 16 independent loads
                af[kt] = ld8(hp + kt * 32);
            const unsigned short* wl = &WL[(size_t)(kh * 1024 + lane) * 8];
#pragma unroll
            for (int kt = 0; kt < 16; ++kt) {
                acc[0] = MF(af[kt], *(const bf16x8*)(wl + (size_t)(0 * 16384 + kt * 512)), acc[0]);
                acc[1] = MF(af[kt], *(const bf16x8*)(wl + (size_t)(1 * 16384 + kt * 512)), acc[1]);
                acc[2] = MF(af[kt], *(const bf16x8*)(wl + (size_t)(2 * 16384 + kt * 512)), acc[2]);
                acc[3] = MF(af[kt], *(const bf16x8*)(wl + (size_t)(3 * 16384 + kt * 512)), acc[3]);
            }
        }

        // ---- 2-phase kt-half reduction into gsum ----
        if (kh == 0) {
#pragma unroll
            for (int g = 0; g < 4; ++g)
#pragma unroll
                for (int r = 0; r < 4; ++r)
                    gsum[mg * 16 + quad * 4 + r][g * 16 + row] = acc[g][r];
        }
        __syncthreads();
        if (kh == 1) {
#pragma unroll
            for (int g = 0; g < 4; ++g)
#pragma unroll
                for (int r = 0; r < 4; ++r)
                    gsum[mg * 16 + quad * 4 + r][g * 16 + row] += acc[g][r];
        }
        __syncthreads();

        // ---- elementwise update: j-pair per thread, private state in regs ----
        {
            const float gi0 = gsum[lb][ 0 + lj]     + bfu2f(xq[0]);
            const float gf0 = gsum[lb][16 + lj]     + bfu2f(xq[1]);
            const float gg0 = gsum[lb][32 + lj]     + bfu2f(xq[2]);
            const float go0 = gsum[lb][48 + lj]     + bfu2f(xq[3]);
            const float gi1 = gsum[lb][ 0 + lj + 1] + bfu2f(xq[4]);
            const float gf1 = gsum[lb][16 + lj + 1] + bfu2f(xq[5]);
            const float gg1 = gsum[lb][32 + lj + 1] + bfu2f(xq[6]);
            const float go1 = gsum[lb][48 + lj + 1] + bfu2f(xq[7]);
            float hv0, hv1;
            if (t < slen[lb]) {
                c_r0 = fsig(gf0) * c_r0 + fsig(gi0) * ftanh(gg0);
                c_r1 = fsig(gf1) * c_r1 + fsig(gi1) * ftanh(gg1);
                hv0 = fsig(go0) * ftanh(c_r0);
                hv1 = fsig(go1) * ftanh(c_r1);
            } else {
                hv0 = hp0;  hv1 = hp1;             // frozen past seq end
            }
            hp0 = hv0;  hp1 = hv1;
            const unsigned hb = (unsigned)f2bu(hv0) | ((unsigned)f2bu(hv1) << 16);
            // h: agent-coherent store into this step's rotating buffer
            __hip_atomic_store(
                reinterpret_cast<unsigned*>(g_hb[wb]) + (idx >> 1), hb,
                __ATOMIC_RELAXED, __HIP_MEMORY_SCOPE_AGENT);
            if (layer == 0) {
                *reinterpret_cast<unsigned*>(&g_seq[(size_t)t * BB * HH + idx]) = hb;
            } else {
                float2 o;  o.x = hv0;  o.y = hv1;
                *reinterpret_cast<float2*>(&out[(size_t)t * BB * HH + idx]) = o;
            }
        }

        if (s + 1 < CHT) {
            // prefetch next step's xg (g_xg immutable during the chunk)
            xq = *reinterpret_cast<const us8*>(
                g_xg + (size_t)(s + 1) * BB * G4 + xoff);

            // ---- group barrier: release = syncthreads-drain + flag store ----
            __syncthreads();   // s_waitcnt vmcnt(0): all h stores acked at IF
            const unsigned want = base + (unsigned)s + 1u;
            if (tid == 0)
                __hip_atomic_store(&g_arrive[bh][jg][0], want,
                                   __ATOMIC_RELAXED, __HIP_MEMORY_SCOPE_AGENT);
            if (wv == 0) {                                 // lane l watches block l
                unsigned v;
                do {
                    v = __hip_atomic_load(&g_arrive[bh][lane][0],
                                          __ATOMIC_RELAXED, __HIP_MEMORY_SCOPE_AGENT);
                    if (v < want) __builtin_amdgcn_s_sleep(1);
                } while (__any(v < want));
            }
            __syncthreads();
        }
    }

    // ---- chunk end: persist c ----
    float2 cc;  cc.x = c_r0;  cc.y = c_r1;
    *reinterpret_cast<float2*>(&g_c[idx]) = cc;
}

// ---------------- small utility kernels ----------------
__global__ __launch_bounds__(256) void finish_layer(float* __restrict__ hn,
                                                    float* __restrict__ cn)
{
    const int i = blockIdx.x * 256 + threadIdx.x;
    // last step of last chunk (s=15) wrote buffer 0
    const unsigned short* hfin = reinterpret_cast<const unsigned short*>(g_hb[0]);
    hn[i] = bfu2f(hfin[i]);
    cn[i] = g_c[i];
}

// =============================================================
// host launcher — plain kernel launches ONLY (graph-capture safe)
// =============================================================
extern "C" void kernel_launch(void* const* d_in, const int* in_sizes, int n_in,
                              void* d_out, int out_size, void* d_ws, size_t ws_size,
                              hipStream_t stream)
{
    const float* x        = (const float*)d_in[0];  // (T,B,D)   f32
    const float* features = (const float*)d_in[1];  // (B,F)     f32
    const float* Wih      = (const float*)d_in[2];  // (L,4H,D)  f32
    const float* Whh      = (const float*)d_in[3];  // (L,4H,H)  f32
    const float* Wfh      = (const float*)d_in[4];  // (L,4H,F)  f32
    const float* bvec     = (const float*)d_in[5];  // (L,4H)    f32
    const int*   length   = (const int*)d_in[6];    // (B,)
    float* out = (float*)d_out;                     // f32 outputs

    const size_t nX = (size_t)TT * BB * DD;
    const size_t nW = (size_t)2 * G4 * 1024;
    const size_t nF = (size_t)BB * 1024;
    cvt_bf16<<<(int)(nX / 1024), 256, 0, stream>>>(0, x, nX);
    cvt_bf16<<<(int)(nW / 1024), 256, 0, stream>>>(1, Wih, nW);
    cvt_bf16<<<(int)(nW / 1024), 256, 0, stream>>>(2, Whh, nW);
    cvt_bf16<<<(int)(nW / 1024), 256, 0, stream>>>(3, Wfh, nW);
    cvt_bf16<<<(int)(nF / 1024), 256, 0, stream>>>(4, features, nF);

    float* out_hn = out + (size_t)TT * BB * HH;
    float* out_cn = out_hn + (size_t)2 * BB * HH;

    for (int l = 0; l < 2; ++l) {
        const size_t w_off = (size_t)l * G4 * 1024;

        gemm_featb<<<dim3(G4 / 64, BB / 128), 256, 0, stream>>>(
            w_off, bvec + (size_t)l * G4);

        for (int c0 = 0; c0 < TT; c0 += CHT) {
            // g_xg = g_seq[chunk] @ Wih[l]^T + g_featb  (bf16, gate-interleaved)
            gemm_xg<<<dim3(G4 / 128, CHT * BB / 128), 256, 0, stream>>>(
                (size_t)c0 * BB * DD, w_off);

            // 16 recurrent steps, one persistent launch with group barriers
            lstm_chunk<<<256, 512, 0, stream>>>(length, out, c0, l);
        }

        finish_layer<<<BB * HH / 256, 256, 0, stream>>>(
            out_hn + (size_t)l * BB * HH, out_cn + (size_t)l * BB * HH);
    }
}

// Round 10
// 1754.253 us; speedup vs baseline: 1.9486x; 1.0424x over previous
//
#include <hip/hip_runtime.h>
#include <hip/hip_bf16.h>

// ---------------- problem shape ----------------
#define TT 64
#define BB 256
#define DD 1024
#define HH 1024
#define G4 4096    // 4*H
#define CHT 16     // xg chunk length (timesteps); 4 chunks cover T=64

typedef __bf16 bf16x8 __attribute__((ext_vector_type(8)));
typedef float  f32x4  __attribute__((ext_vector_type(4)));
typedef unsigned short us8 __attribute__((ext_vector_type(8)));
typedef unsigned long long u64;

// ---------------- static device scratch (~127 MB) ----------------
__device__ unsigned short g_seq [(size_t)TT * BB * 1024];  // x (bf16) -> layer-1 h seq   32 MB
__device__ unsigned short g_Wih [(size_t)2 * G4 * 1024];   // 16 MB
__device__ unsigned short g_Whh [(size_t)2 * G4 * 1024];   // 16 MB
__device__ unsigned short g_Wfh [(size_t)2 * G4 * 1024];   // 16 MB
__device__ unsigned short g_feat[(size_t)BB * 1024];       // 0.5 MB
__device__ unsigned short g_xg  [(size_t)CHT * BB * G4];   // bf16 gates chunk (GATE-INTERLEAVED: [m][j*4+g])
// h rotates through CHT per-step buffers (8 MB). Step s WRITES buffer
// CHT-1-s (agent-atomic, write-through to coherence point) and READS buffer
// CHT-s (s=0: buffer 0 = previous kernel's last write) with PLAIN CACHED
// loads: within a chunk each buffer is read exactly once, strictly after its
// unique write, and never touched earlier in the kernel -> no stale L2 line
// can exist; kernel-launch acquire invalidates between chunks. (R9-proven:
// 189 -> 127 us.)
__device__ u64            g_hb  [CHT][(size_t)BB * HH / 4];
__device__ float          g_featb[(size_t)BB * G4];        // f32 feat@Wfh^T+b, nn-layout  4 MB
__device__ float          g_c   [(size_t)BB * HH];         // f32 cell state               1 MB

// distributed barrier flags: [bh group 0..3][jg block 0..63][64B pad].
// Monotonic epochs (never reset -> graph-replay safe); one cacheline per
// block -> parallel arrivals, parallel 64-lane polls (R4..R9-proven).
__device__ unsigned g_arrive[4][64][16];

__device__ __forceinline__ bf16x8 ld8(const __hip_bfloat16* p) {
    return *reinterpret_cast<const bf16x8*>(p);
}
__device__ __forceinline__ __hip_bfloat16* BP(unsigned short* p) {
    return reinterpret_cast<__hip_bfloat16*>(p);
}
__device__ __forceinline__ const __hip_bfloat16* BPc(const unsigned short* p) {
    return reinterpret_cast<const __hip_bfloat16*>(p);
}
__device__ __forceinline__ f32x4 MF(bf16x8 a, bf16x8 b, f32x4 c) {
    return __builtin_amdgcn_mfma_f32_16x16x32_bf16(a, b, c, 0, 0, 0);
}
__device__ __forceinline__ float fsig(float x) {
    return 1.0f / (1.0f + __expf(-x));
}
__device__ __forceinline__ float ftanh(float x) {   // clamped: exp never inf
    const float x2 = fminf(fmaxf(2.0f * x, -30.0f), 30.0f);
    const float e  = __expf(x2);
    return (e - 1.0f) / (e + 1.0f);
}
__device__ __forceinline__ float bfu2f(unsigned short u) {  // bf16 bits -> f32
    return __uint_as_float((unsigned)u << 16);
}
__device__ __forceinline__ unsigned short f2bu(float x) {   // f32 -> bf16 bits
    __hip_bfloat16 h = __float2bfloat16(x);
    return *reinterpret_cast<unsigned short*>(&h);
}

// direct global->LDS async copy, 16B per lane
typedef unsigned int u32_g __attribute__((address_space(1)));
typedef unsigned int u32_l __attribute__((address_space(3)));
__device__ __forceinline__ void gload16(const void* g, void* l) {
    __builtin_amdgcn_global_load_lds((const u32_g*)g, (u32_l*)l, 16, 0, 0);
}

// =============================================================
// R10: ALL f32->bf16 conversions fused in ONE launch (was 5 launches).
// Range-dispatched on global element index; all range sizes are
// multiples of 4, so a 4-elem workitem never straddles buffers.
// =============================================================
__global__ __launch_bounds__(256) void cvt_all(
    const float* __restrict__ x,   const float* __restrict__ Wih,
    const float* __restrict__ Whh, const float* __restrict__ Wfh,
    const float* __restrict__ feat)
{
    const size_t nX = (size_t)TT * BB * DD;
    const size_t nW = (size_t)2 * G4 * 1024;
    size_t i = ((size_t)blockIdx.x * 256 + threadIdx.x) * 4;
    const float* s;  unsigned short* d;  size_t off;
    if      (i < nX)          { s = x;    d = g_seq;  off = 0; }
    else if (i < nX + nW)     { s = Wih;  d = g_Wih;  off = nX; }
    else if (i < nX + 2 * nW) { s = Whh;  d = g_Whh;  off = nX + nW; }
    else if (i < nX + 3 * nW) { s = Wfh;  d = g_Wfh;  off = nX + 2 * nW; }
    else                      { s = feat; d = g_feat; off = nX + 3 * nW; }
    const size_t k = i - off;
    float4 v = *reinterpret_cast<const float4*>(s + k);
    __hip_bfloat16* db = BP(d) + k;
    db[0] = __float2bfloat16(v.x);
    db[1] = __float2bfloat16(v.y);
    db[2] = __float2bfloat16(v.z);
    db[3] = __float2bfloat16(v.w);
}

// =============================================================
// Small-M featb GEMM: g_featb[256, nn(4096)] = feat @ Wfh[l]^T + b[l] (f32)
// Stores in GATE-INTERLEAVED nn-layout so gemm_xg's epilogue read is
// contiguous.
// =============================================================
__global__ __launch_bounds__(256) void gemm_featb(size_t w_off,
                                                  const float* __restrict__ bias)
{
    const int tid  = threadIdx.x;
    const int lane = tid & 63, wid = tid >> 6;
    const int row  = lane & 15, quad = lane >> 4;
    const int m_base = blockIdx.y * 128 + (wid >> 1) * 64;
    const int n_base = blockIdx.x * 64  + (wid & 1) * 32;

    const __hip_bfloat16* A = BPc(g_feat);
    const __hip_bfloat16* W = BPc(g_Wfh) + w_off;

    f32x4 acc[4][2] = {};
    const __hip_bfloat16* Ap = A + (size_t)(m_base + row) * 1024 + quad * 8;
    const __hip_bfloat16* Wp = W + (size_t)(n_base + row) * 1024 + quad * 8;

    for (int k0 = 0; k0 < 1024; k0 += 32) {
        bf16x8 a[4], b[2];
#pragma unroll
        for (int i = 0; i < 4; ++i) a[i] = ld8(Ap + (size_t)(16 * i) * 1024 + k0);
#pragma unroll
        for (int j = 0; j < 2; ++j) b[j] = ld8(Wp + (size_t)(16 * j) * 1024 + k0);
#pragma unroll
        for (int i = 0; i < 4; ++i)
#pragma unroll
            for (int j = 0; j < 2; ++j)
                acc[i][j] = MF(a[i], b[j], acc[i][j]);
    }
#pragma unroll
    for (int i = 0; i < 4; ++i)
#pragma unroll
        for (int j = 0; j < 2; ++j) {
            const int n = n_base + 16 * j + row;
            const int nn = ((n & 1023) << 2) + (n >> 10);   // gate-interleaved
#pragma unroll
            for (int r = 0; r < 4; ++r) {
                const int m = m_base + 16 * i + quad * 4 + r;
                g_featb[(size_t)m * G4 + nn] = acc[i][j][r] + bias[n];
            }
        }
}

// =============================================================
// xg GEMM (chunk): C = g_seq[chunk] @ Wih[l]^T (+featb, ->bf16, nn-layout)
// 128x128 tile, BK=32, double-buffered LDS via global_load_lds(16B),
// involutive both-sides LDS swizzle (R4-verified) + XCD block swizzle.
// GATE-MIXED B tile: LDS B-row p holds Wih row (p&3)*1024 + cb + (p>>2),
// so output nn = cb*4 + p gives contiguous stores + contiguous featb reads.
// =============================================================
__global__ __launch_bounds__(256) void gemm_xg(size_t seq_off, size_t w_off)
{
    __shared__ unsigned short lA[2][128 * 32];
    __shared__ unsigned short lB[2][128 * 32];

    const int tid  = threadIdx.x;
    const int lane = tid & 63, wv = tid >> 6;
    const int row  = lane & 15, quad = lane >> 4;
    const int wr = wv >> 1, wc = wv & 1;

    // XCD swizzle: consecutive tiles land on the same XCD's L2
    const int flat = blockIdx.y * gridDim.x + blockIdx.x;
    const int cpx  = (gridDim.x * gridDim.y) >> 3;
    const int swz  = (flat & 7) * cpx + (flat >> 3);
    const int m_base = (swz / gridDim.x) * 128;
    const int cb     = (swz % gridDim.x) * 32;     // 32 true-column base

    const __hip_bfloat16* A  = BPc(g_seq) + seq_off + (size_t)m_base * 1024;
    const __hip_bfloat16* Wt = BPc(g_Wih) + w_off;

    f32x4 acc[4][4] = {};

    const int sm = (tid >> 3) & 7;                   // == (d>>3)&7 for d=it*256+tid
    auto STAGE = [&](int bf, int kt) {
        const int k0 = kt * 32;
#pragma unroll
        for (int it = 0; it < 2; ++it) {
            const int d = it * 256 + tid;
            const int l = d ^ sm;                    // involutive granule permutation
            const int r  = l >> 2;                   // LDS row p (A: m-row)
            const int kc = k0 + (l & 3) * 8;
            unsigned short* dA = &lA[bf][(size_t)(it * 256 + wv * 64) * 8];
            unsigned short* dB = &lB[bf][(size_t)(it * 256 + wv * 64) * 8];
            gload16(A + (size_t)r * 1024 + kc, dA);
            // gate-mixed B row: p -> Wih row (p&3)*1024 + cb + (p>>2)
            const int nrow = ((r & 3) << 10) + cb + (r >> 2);
            gload16(Wt + (size_t)nrow * 1024 + kc, dB);
        }
    };

    STAGE(0, 0);
    asm volatile("s_waitcnt vmcnt(0)" ::: "memory");
    __syncthreads();

    const int rm = (row >> 1) & 7;                   // == (s>>3)&7 for our read slots

    for (int kt = 0; kt < 32; ++kt) {
        const int cur = kt & 1;
        if (kt + 1 < 32) STAGE(cur ^ 1, kt + 1);

        bf16x8 a[4], b[4];
#pragma unroll
        for (int i = 0; i < 4; ++i) {
            const int s = ((wr * 64 + 16 * i + row) * 4 + quad) ^ rm;
            a[i] = ld8(BPc(&lA[cur][(size_t)s * 8]));
        }
#pragma unroll
        for (int j = 0; j < 4; ++j) {
            const int s = ((wc * 64 + 16 * j + row) * 4 + quad) ^ rm;
            b[j] = ld8(BPc(&lB[cur][(size_t)s * 8]));
        }
#pragma unroll
        for (int i = 0; i < 4; ++i)
#pragma unroll
            for (int j = 0; j < 4; ++j)
                acc[i][j] = MF(a[i], b[j], acc[i][j]);

        asm volatile("s_waitcnt vmcnt(0)" ::: "memory");
        __syncthreads();
    }

#pragma unroll
    for (int i = 0; i < 4; ++i)
#pragma unroll
        for (int j = 0; j < 4; ++j) {
            const int p  = wc * 64 + 16 * j + row;     // tile-local n position
            const int nn = cb * 4 + p;                 // contiguous output index
#pragma unroll
            for (int r = 0; r < 4; ++r) {
                const int m = m_base + wr * 64 + 16 * i + quad * 4 + r;
                float v = acc[i][j][r] + g_featb[(size_t)(m & 255) * G4 + nn];
                BP(g_xg)[(size_t)m * G4 + nn] = __float2bfloat16(v);
            }
        }
}

// =============================================================
// Persistent LSTM chunk: 16 timesteps in ONE launch.
// Grid 256 blocks x 512 thr; block (jg 0..63, bh 0..3): j-cols [jg*16,+16),
// batches [bh*64,+64). Wave (mg,kh) = batch-16 group x kt-half.
// R10: CRITICAL-PATH REORDER. The release drain (__syncthreads' vmcnt(0)
// before the flag store) now covers ONLY the h agent-stores. The out/g_seq
// stores and next-step xq prefetch — which R9 issued before the drain,
// putting a cold L3/HBM read + store acks on the inter-block critical
// path every step — are issued AFTER the flag (they complete during the
// poll / next step's first sync; nothing reads them until after the
// kernel boundary).
// =============================================================
__global__ __launch_bounds__(512, 1) void lstm_chunk(
    const int* __restrict__ length,
    float* __restrict__ out,          // (T,B,H) f32 base (layer-1 writes)
    int c0, int layer)
{
    __shared__ unsigned short WL[64 * 1024];   // 128 KB fragment-ordered Whh
    __shared__ float gsum[64][65];             // 16.6 KB padded exchange
    __shared__ int   slen[64];                 // lengths for this block's batches
    __shared__ unsigned s_base;

    const int tid  = threadIdx.x;
    const int lane = tid & 63, wv = tid >> 6;
    const int row  = lane & 15, quad = lane >> 4;
    const int mg = wv >> 1, kh = wv & 1;       // batch-16 group, kt-half
    const int jg = blockIdx.x >> 2, bh = blockIdx.x & 3;
    const int j0 = jg * 16;
    const int bb0 = bh * 64;

    if (tid == 0)
        s_base = __hip_atomic_load(&g_arrive[bh][jg][0], __ATOMIC_RELAXED,
                                   __HIP_MEMORY_SCOPE_AGENT);
    if (tid < 64) slen[tid] = length[bb0 + tid];

    {   // ---- load Whh slice, fragment-ordered (once per chunk) ----
        const __hip_bfloat16* Whh = BPc(g_Whh) + (size_t)layer * G4 * 1024;
#pragma unroll
        for (int i = 0; i < 16; ++i) {
            const int G = tid + i * 512;                 // 0..8191 granules
            const int g = G >> 11, kt = (G >> 6) & 31, l = G & 63;
            *reinterpret_cast<bf16x8*>(&WL[(size_t)G * 8]) =
                ld8(Whh + (size_t)(g * 1024 + j0 + (l & 15)) * 1024
                        + kt * 32 + (l >> 4) * 8);
        }
    }

    // ---- per-thread elementwise mapping: one j-PAIR per thread ----
    const int lb  = tid >> 3;                  // batch row 0..63
    const int lj  = (tid & 7) * 2;             // col pair 0,2,..,14
    const size_t idx  = (size_t)(bb0 + lb) * HH + j0 + lj;            // even
    const size_t xoff = (size_t)(bb0 + lb) * G4 + (size_t)(j0 + lj) * 4;  // 16B-aligned
    float c_r0, c_r1, hp0, hp1;
    if (c0 == 0) { c_r0 = c_r1 = hp0 = hp1 = 0.0f; }
    else {
        const float2 cc = *reinterpret_cast<const float2*>(&g_c[idx]);
        c_r0 = cc.x;  c_r1 = cc.y;
        // previous kernel's last write landed in buffer 0
        const unsigned hu = reinterpret_cast<const unsigned*>(g_hb[0])[idx >> 1];
        hp0 = bfu2f((unsigned short)(hu & 0xffffu));
        hp1 = bfu2f((unsigned short)(hu >> 16));
    }
    // prefetch xg for step 0 (gate-interleaved: 8 ushorts = both cols x 4 gates)
    us8 xq = *reinterpret_cast<const us8*>(g_xg + xoff);

    __syncthreads();
    const unsigned base = s_base;

    for (int s = 0; s < CHT; ++s) {
        const int t = c0 + s;
        const int wb = CHT - 1 - s;                     // write buffer
        const int rb = (s == 0) ? 0 : (CHT - s);        // read buffer (= prev write)

        f32x4 acc[4] = {};          // 4 gates, 16 batches, this kt-half
        if (t > 0) {
            // h A-frags: PLAIN cached 16B loads (L2-served; see g_hb comment)
            const __hip_bfloat16* hp = reinterpret_cast<const __hip_bfloat16*>(g_hb[rb])
                + (size_t)(bb0 + mg * 16 + row) * HH + kh * 512 + quad * 8;
            bf16x8 af[16];
#pragma unroll
            for (int kt = 0; kt < 16; ++kt)             // 16 independent loads
                af[kt] = ld8(hp + kt * 32);
            const unsigned short* wl = &WL[(size_t)(kh * 1024 + lane) * 8];
#pragma unroll
            for (int kt = 0; kt < 16; ++kt) {
                acc[0] = MF(af[kt], *(const bf16x8*)(wl + (size_t)(0 * 16384 + kt * 512)), acc[0]);
                acc[1] = MF(af[kt], *(const bf16x8*)(wl + (size_t)(1 * 16384 + kt * 512)), acc[1]);
                acc[2] = MF(af[kt], *(const bf16x8*)(wl + (size_t)(2 * 16384 + kt * 512)), acc[2]);
                acc[3] = MF(af[kt], *(const bf16x8*)(wl + (size_t)(3 * 16384 + kt * 512)), acc[3]);
            }
        }

        // ---- 2-phase kt-half reduction into gsum ----
        if (kh == 0) {
#pragma unroll
            for (int g = 0; g < 4; ++g)
#pragma unroll
                for (int r = 0; r < 4; ++r)
                    gsum[mg * 16 + quad * 4 + r][g * 16 + row] = acc[g][r];
        }
        __syncthreads();
        if (kh == 1) {
#pragma unroll
            for (int g = 0; g < 4; ++g)
#pragma unroll
                for (int r = 0; r < 4; ++r)
                    gsum[mg * 16 + quad * 4 + r][g * 16 + row] += acc[g][r];
        }
        __syncthreads();

        // ---- elementwise update: compute h, issue ONLY the h store ----
        float hv0, hv1;
        {
            const float gi0 = gsum[lb][ 0 + lj]     + bfu2f(xq[0]);
            const float gf0 = gsum[lb][16 + lj]     + bfu2f(xq[1]);
            const float gg0 = gsum[lb][32 + lj]     + bfu2f(xq[2]);
            const float go0 = gsum[lb][48 + lj]     + bfu2f(xq[3]);
            const float gi1 = gsum[lb][ 0 + lj + 1] + bfu2f(xq[4]);
            const float gf1 = gsum[lb][16 + lj + 1] + bfu2f(xq[5]);
            const float gg1 = gsum[lb][32 + lj + 1] + bfu2f(xq[6]);
            const float go1 = gsum[lb][48 + lj + 1] + bfu2f(xq[7]);
            if (t < slen[lb]) {
                c_r0 = fsig(gf0) * c_r0 + fsig(gi0) * ftanh(gg0);
                c_r1 = fsig(gf1) * c_r1 + fsig(gi1) * ftanh(gg1);
                hv0 = fsig(go0) * ftanh(c_r0);
                hv1 = fsig(go1) * ftanh(c_r1);
            } else {
                hv0 = hp0;  hv1 = hp1;             // frozen past seq end
            }
            hp0 = hv0;  hp1 = hv1;
            const unsigned hb = (unsigned)f2bu(hv0) | ((unsigned)f2bu(hv1) << 16);
            // h: agent-coherent store into this step's rotating buffer
            __hip_atomic_store(
                reinterpret_cast<unsigned*>(g_hb[wb]) + (idx >> 1), hb,
                __ATOMIC_RELAXED, __HIP_MEMORY_SCOPE_AGENT);
        }

        if (s + 1 < CHT) {
            // ---- release: drain h stores ONLY, then flag immediately ----
            __syncthreads();   // s_waitcnt vmcnt(0): only h stores in flight
            const unsigned want = base + (unsigned)s + 1u;
            if (tid == 0)
                __hip_atomic_store(&g_arrive[bh][jg][0], want,
                                   __ATOMIC_RELAXED, __HIP_MEMORY_SCOPE_AGENT);

            // ---- off the release path: seq/out stores + xq prefetch ----
            {
                const unsigned hb = (unsigned)f2bu(hv0) | ((unsigned)f2bu(hv1) << 16);
                if (layer == 0) {
                    *reinterpret_cast<unsigned*>(&g_seq[(size_t)t * BB * HH + idx]) = hb;
                } else {
                    float2 o;  o.x = hv0;  o.y = hv1;
                    *reinterpret_cast<float2*>(&out[(size_t)t * BB * HH + idx]) = o;
                }
                xq = *reinterpret_cast<const us8*>(
                    g_xg + (size_t)(s + 1) * BB * G4 + xoff);
            }

            if (wv == 0) {                                 // lane l watches block l
                unsigned v;
                do {
                    v = __hip_atomic_load(&g_arrive[bh][lane][0],
                                          __ATOMIC_RELAXED, __HIP_MEMORY_SCOPE_AGENT);
                    if (v < want) __builtin_amdgcn_s_sleep(1);
                } while (__any(v < want));
            }
            __syncthreads();
        } else {
            // final step: issue the deferred stores before kernel end
            const unsigned hb = (unsigned)f2bu(hv0) | ((unsigned)f2bu(hv1) << 16);
            if (layer == 0) {
                *reinterpret_cast<unsigned*>(&g_seq[(size_t)t * BB * HH + idx]) = hb;
            } else {
                float2 o;  o.x = hv0;  o.y = hv1;
                *reinterpret_cast<float2*>(&out[(size_t)t * BB * HH + idx]) = o;
            }
        }
    }

    // ---- chunk end: persist c ----
    float2 cc;  cc.x = c_r0;  cc.y = c_r1;
    *reinterpret_cast<float2*>(&g_c[idx]) = cc;
}

// ---------------- small utility kernels ----------------
__global__ __launch_bounds__(256) void finish_layer(float* __restrict__ hn,
                                                    float* __restrict__ cn)
{
    const int i = blockIdx.x * 256 + threadIdx.x;
    // last step of last chunk (s=15) wrote buffer 0
    const unsigned short* hfin = reinterpret_cast<const unsigned short*>(g_hb[0]);
    hn[i] = bfu2f(hfin[i]);
    cn[i] = g_c[i];
}

// =============================================================
// host launcher — plain kernel launches ONLY (graph-capture safe)
// =============================================================
extern "C" void kernel_launch(void* const* d_in, const int* in_sizes, int n_in,
                              void* d_out, int out_size, void* d_ws, size_t ws_size,
                              hipStream_t stream)
{
    const float* x        = (const float*)d_in[0];  // (T,B,D)   f32
    const float* features = (const float*)d_in[1];  // (B,F)     f32
    const float* Wih      = (const float*)d_in[2];  // (L,4H,D)  f32
    const float* Whh      = (const float*)d_in[3];  // (L,4H,H)  f32
    const float* Wfh      = (const float*)d_in[4];  // (L,4H,F)  f32
    const float* bvec     = (const float*)d_in[5];  // (L,4H)    f32
    const int*   length   = (const int*)d_in[6];    // (B,)
    float* out = (float*)d_out;                     // f32 outputs

    // one fused conversion launch (R10): total elems = nX + 3*nW + nF
    const size_t nTot = (size_t)TT * BB * DD + 3 * ((size_t)2 * G4 * 1024)
                      + (size_t)BB * 1024;
    cvt_all<<<(int)(nTot / 1024), 256, 0, stream>>>(x, Wih, Whh, Wfh, features);

    float* out_hn = out + (size_t)TT * BB * HH;
    float* out_cn = out_hn + (size_t)2 * BB * HH;

    for (int l = 0; l < 2; ++l) {
        const size_t w_off = (size_t)l * G4 * 1024;

        gemm_featb<<<dim3(G4 / 64, BB / 128), 256, 0, stream>>>(
            w_off, bvec + (size_t)l * G4);

        for (int c0 = 0; c0 < TT; c0 += CHT) {
            // g_xg = g_seq[chunk] @ Wih[l]^T + g_featb  (bf16, gate-interleaved)
            gemm_xg<<<dim3(G4 / 128, CHT * BB / 128), 256, 0, stream>>>(
                (size_t)c0 * BB * DD, w_off);

            // 16 recurrent steps, one persistent launch with group barriers
            lstm_chunk<<<256, 512, 0, stream>>>(length, out, c0, l);
        }

        finish_layer<<<BB * HH / 256, 256, 0, stream>>>(
            out_hn + (size_t)l * BB * HH, out_cn + (size_t)l * BB * HH);
    }
}

// Round 11
// 1668.275 us; speedup vs baseline: 2.0491x; 1.0515x over previous
//
#include <hip/hip_runtime.h>
#include <hip/hip_bf16.h>

// ---------------- problem shape ----------------
#define TT 64
#define BB 256
#define DD 1024
#define HH 1024
#define G4 4096    // 4*H
#define CHT 32     // R11: xg chunk length; 2 chunks cover T=64 (was 16/4)

typedef __bf16 bf16x8 __attribute__((ext_vector_type(8)));
typedef float  f32x4  __attribute__((ext_vector_type(4)));
typedef unsigned short us8 __attribute__((ext_vector_type(8)));
typedef unsigned long long u64;

// ---------------- static device scratch (~167 MB) ----------------
__device__ unsigned short g_seq [(size_t)TT * BB * 1024];  // x (bf16) -> layer-1 h seq   32 MB
__device__ unsigned short g_Wih [(size_t)2 * G4 * 1024];   // 16 MB
__device__ unsigned short g_Whh [(size_t)2 * G4 * 1024];   // 16 MB
__device__ unsigned short g_Wfh [(size_t)2 * G4 * 1024];   // 16 MB
__device__ unsigned short g_feat[(size_t)BB * 1024];       // 0.5 MB
__device__ unsigned short g_xg  [(size_t)CHT * BB * G4];   // bf16 gates chunk (GATE-INTERLEAVED)  64 MB
// h rotates through CHT per-step buffers (16.8 MB). Step s WRITES buffer
// CHT-1-s (agent-atomic, write-through to coherence point) and READS buffer
// CHT-s (s=0: buffer 0 = previous kernel's last write) with PLAIN CACHED
// loads: within a kernel each buffer is read exactly once, strictly after
// its unique write (buffer 0: read s=0 precedes write s=CHT-1) -> no stale
// L2 line can exist; kernel-launch acquire invalidates between chunks.
// (R9-proven mechanism: 189 -> 127 us.)
__device__ u64            g_hb  [CHT][(size_t)BB * HH / 4];
__device__ float          g_featb[(size_t)BB * G4];        // f32 feat@Wfh^T+b, nn-layout  4 MB
__device__ float          g_c   [(size_t)BB * HH];         // f32 cell state               1 MB

// distributed barrier flags: [bh group 0..3][jg block 0..63][64B pad].
// Monotonic epochs (never reset -> graph-replay safe); one cacheline per
// block -> parallel arrivals, parallel 64-lane polls (R4..R10-proven).
__device__ unsigned g_arrive[4][64][16];

__device__ __forceinline__ bf16x8 ld8(const __hip_bfloat16* p) {
    return *reinterpret_cast<const bf16x8*>(p);
}
__device__ __forceinline__ __hip_bfloat16* BP(unsigned short* p) {
    return reinterpret_cast<__hip_bfloat16*>(p);
}
__device__ __forceinline__ const __hip_bfloat16* BPc(const unsigned short* p) {
    return reinterpret_cast<const __hip_bfloat16*>(p);
}
__device__ __forceinline__ f32x4 MF(bf16x8 a, bf16x8 b, f32x4 c) {
    return __builtin_amdgcn_mfma_f32_16x16x32_bf16(a, b, c, 0, 0, 0);
}
__device__ __forceinline__ float fsig(float x) {
    return 1.0f / (1.0f + __expf(-x));
}
__device__ __forceinline__ float ftanh(float x) {   // clamped: exp never inf
    const float x2 = fminf(fmaxf(2.0f * x, -30.0f), 30.0f);
    const float e  = __expf(x2);
    return (e - 1.0f) / (e + 1.0f);
}
__device__ __forceinline__ float bfu2f(unsigned short u) {  // bf16 bits -> f32
    return __uint_as_float((unsigned)u << 16);
}
__device__ __forceinline__ unsigned short f2bu(float x) {   // f32 -> bf16 bits
    __hip_bfloat16 h = __float2bfloat16(x);
    return *reinterpret_cast<unsigned short*>(&h);
}

// direct global->LDS async copy, 16B per lane
typedef unsigned int u32_g __attribute__((address_space(1)));
typedef unsigned int u32_l __attribute__((address_space(3)));
__device__ __forceinline__ void gload16(const void* g, void* l) {
    __builtin_amdgcn_global_load_lds((const u32_g*)g, (u32_l*)l, 16, 0, 0);
}

// =============================================================
// ALL f32->bf16 conversions fused in ONE launch (R10-proven).
// =============================================================
__global__ __launch_bounds__(256) void cvt_all(
    const float* __restrict__ x,   const float* __restrict__ Wih,
    const float* __restrict__ Whh, const float* __restrict__ Wfh,
    const float* __restrict__ feat)
{
    const size_t nX = (size_t)TT * BB * DD;
    const size_t nW = (size_t)2 * G4 * 1024;
    size_t i = ((size_t)blockIdx.x * 256 + threadIdx.x) * 4;
    const float* s;  unsigned short* d;  size_t off;
    if      (i < nX)          { s = x;    d = g_seq;  off = 0; }
    else if (i < nX + nW)     { s = Wih;  d = g_Wih;  off = nX; }
    else if (i < nX + 2 * nW) { s = Whh;  d = g_Whh;  off = nX + nW; }
    else if (i < nX + 3 * nW) { s = Wfh;  d = g_Wfh;  off = nX + 2 * nW; }
    else                      { s = feat; d = g_feat; off = nX + 3 * nW; }
    const size_t k = i - off;
    float4 v = *reinterpret_cast<const float4*>(s + k);
    __hip_bfloat16* db = BP(d) + k;
    db[0] = __float2bfloat16(v.x);
    db[1] = __float2bfloat16(v.y);
    db[2] = __float2bfloat16(v.z);
    db[3] = __float2bfloat16(v.w);
}

// =============================================================
// Small-M featb GEMM: g_featb[256, nn(4096)] = feat @ Wfh[l]^T + b[l] (f32)
// Stores in GATE-INTERLEAVED nn-layout so gemm_xg's epilogue read is
// contiguous.
// =============================================================
__global__ __launch_bounds__(256) void gemm_featb(size_t w_off,
                                                  const float* __restrict__ bias)
{
    const int tid  = threadIdx.x;
    const int lane = tid & 63, wid = tid >> 6;
    const int row  = lane & 15, quad = lane >> 4;
    const int m_base = blockIdx.y * 128 + (wid >> 1) * 64;
    const int n_base = blockIdx.x * 64  + (wid & 1) * 32;

    const __hip_bfloat16* A = BPc(g_feat);
    const __hip_bfloat16* W = BPc(g_Wfh) + w_off;

    f32x4 acc[4][2] = {};
    const __hip_bfloat16* Ap = A + (size_t)(m_base + row) * 1024 + quad * 8;
    const __hip_bfloat16* Wp = W + (size_t)(n_base + row) * 1024 + quad * 8;

    for (int k0 = 0; k0 < 1024; k0 += 32) {
        bf16x8 a[4], b[2];
#pragma unroll
        for (int i = 0; i < 4; ++i) a[i] = ld8(Ap + (size_t)(16 * i) * 1024 + k0);
#pragma unroll
        for (int j = 0; j < 2; ++j) b[j] = ld8(Wp + (size_t)(16 * j) * 1024 + k0);
#pragma unroll
        for (int i = 0; i < 4; ++i)
#pragma unroll
            for (int j = 0; j < 2; ++j)
                acc[i][j] = MF(a[i], b[j], acc[i][j]);
    }
#pragma unroll
    for (int i = 0; i < 4; ++i)
#pragma unroll
        for (int j = 0; j < 2; ++j) {
            const int n = n_base + 16 * j + row;
            const int nn = ((n & 1023) << 2) + (n >> 10);   // gate-interleaved
#pragma unroll
            for (int r = 0; r < 4; ++r) {
                const int m = m_base + 16 * i + quad * 4 + r;
                g_featb[(size_t)m * G4 + nn] = acc[i][j][r] + bias[n];
            }
        }
}

// =============================================================
// xg GEMM (chunk): C = g_seq[chunk] @ Wih[l]^T (+featb, ->bf16, nn-layout)
// 128x128 tile, BK=32, double-buffered LDS via global_load_lds(16B),
// involutive both-sides LDS swizzle + XCD block swizzle + gate-mixed B
// tile (contiguous stores/featb reads). R11: grid 2048 blocks (CHT=32).
// =============================================================
__global__ __launch_bounds__(256) void gemm_xg(size_t seq_off, size_t w_off)
{
    __shared__ unsigned short lA[2][128 * 32];
    __shared__ unsigned short lB[2][128 * 32];

    const int tid  = threadIdx.x;
    const int lane = tid & 63, wv = tid >> 6;
    const int row  = lane & 15, quad = lane >> 4;
    const int wr = wv >> 1, wc = wv & 1;

    // XCD swizzle: consecutive tiles land on the same XCD's L2
    const int flat = blockIdx.y * gridDim.x + blockIdx.x;
    const int cpx  = (gridDim.x * gridDim.y) >> 3;
    const int swz  = (flat & 7) * cpx + (flat >> 3);
    const int m_base = (swz / gridDim.x) * 128;
    const int cb     = (swz % gridDim.x) * 32;     // 32 true-column base

    const __hip_bfloat16* A  = BPc(g_seq) + seq_off + (size_t)m_base * 1024;
    const __hip_bfloat16* Wt = BPc(g_Wih) + w_off;

    f32x4 acc[4][4] = {};

    const int sm = (tid >> 3) & 7;                   // == (d>>3)&7 for d=it*256+tid
    auto STAGE = [&](int bf, int kt) {
        const int k0 = kt * 32;
#pragma unroll
        for (int it = 0; it < 2; ++it) {
            const int d = it * 256 + tid;
            const int l = d ^ sm;                    // involutive granule permutation
            const int r  = l >> 2;                   // LDS row p (A: m-row)
            const int kc = k0 + (l & 3) * 8;
            unsigned short* dA = &lA[bf][(size_t)(it * 256 + wv * 64) * 8];
            unsigned short* dB = &lB[bf][(size_t)(it * 256 + wv * 64) * 8];
            gload16(A + (size_t)r * 1024 + kc, dA);
            // gate-mixed B row: p -> Wih row (p&3)*1024 + cb + (p>>2)
            const int nrow = ((r & 3) << 10) + cb + (r >> 2);
            gload16(Wt + (size_t)nrow * 1024 + kc, dB);
        }
    };

    STAGE(0, 0);
    asm volatile("s_waitcnt vmcnt(0)" ::: "memory");
    __syncthreads();

    const int rm = (row >> 1) & 7;                   // == (s>>3)&7 for our read slots

    for (int kt = 0; kt < 32; ++kt) {
        const int cur = kt & 1;
        if (kt + 1 < 32) STAGE(cur ^ 1, kt + 1);

        bf16x8 a[4], b[4];
#pragma unroll
        for (int i = 0; i < 4; ++i) {
            const int s = ((wr * 64 + 16 * i + row) * 4 + quad) ^ rm;
            a[i] = ld8(BPc(&lA[cur][(size_t)s * 8]));
        }
#pragma unroll
        for (int j = 0; j < 4; ++j) {
            const int s = ((wc * 64 + 16 * j + row) * 4 + quad) ^ rm;
            b[j] = ld8(BPc(&lB[cur][(size_t)s * 8]));
        }
#pragma unroll
        for (int i = 0; i < 4; ++i)
#pragma unroll
            for (int j = 0; j < 4; ++j)
                acc[i][j] = MF(a[i], b[j], acc[i][j]);

        asm volatile("s_waitcnt vmcnt(0)" ::: "memory");
        __syncthreads();
    }

#pragma unroll
    for (int i = 0; i < 4; ++i)
#pragma unroll
        for (int j = 0; j < 4; ++j) {
            const int p  = wc * 64 + 16 * j + row;     // tile-local n position
            const int nn = cb * 4 + p;                 // contiguous output index
#pragma unroll
            for (int r = 0; r < 4; ++r) {
                const int m = m_base + wr * 64 + 16 * i + quad * 4 + r;
                float v = acc[i][j][r] + g_featb[(size_t)(m & 255) * G4 + nn];
                BP(g_xg)[(size_t)m * G4 + nn] = __float2bfloat16(v);
            }
        }
}

// =============================================================
// Persistent LSTM chunk: CHT=32 timesteps in ONE launch (R11).
// Grid 256 blocks x 512 thr; block (jg 0..63, bh 0..3): j-cols [jg*16,+16),
// batches [bh*64,+64). Wave (mg,kh) = batch-16 group x kt-half.
// Whh slice (128 KB) loaded once per launch — now amortized over 32 steps.
// Release drain covers ONLY h agent-stores; out/g_seq stores + xq prefetch
// issued after the flag (R10-proven). h reads are plain cached loads from
// the rotating per-step buffer (R9-proven).
// =============================================================
__global__ __launch_bounds__(512, 1) void lstm_chunk(
    const int* __restrict__ length,
    float* __restrict__ out,          // (T,B,H) f32 base (layer-1 writes)
    int c0, int layer)
{
    __shared__ unsigned short WL[64 * 1024];   // 128 KB fragment-ordered Whh
    __shared__ float gsum[64][65];             // 16.6 KB padded exchange
    __shared__ int   slen[64];                 // lengths for this block's batches
    __shared__ unsigned s_base;

    const int tid  = threadIdx.x;
    const int lane = tid & 63, wv = tid >> 6;
    const int row  = lane & 15, quad = lane >> 4;
    const int mg = wv >> 1, kh = wv & 1;       // batch-16 group, kt-half
    const int jg = blockIdx.x >> 2, bh = blockIdx.x & 3;
    const int j0 = jg * 16;
    const int bb0 = bh * 64;

    if (tid == 0)
        s_base = __hip_atomic_load(&g_arrive[bh][jg][0], __ATOMIC_RELAXED,
                                   __HIP_MEMORY_SCOPE_AGENT);
    if (tid < 64) slen[tid] = length[bb0 + tid];

    {   // ---- load Whh slice, fragment-ordered (once per launch) ----
        const __hip_bfloat16* Whh = BPc(g_Whh) + (size_t)layer * G4 * 1024;
#pragma unroll
        for (int i = 0; i < 16; ++i) {
            const int G = tid + i * 512;                 // 0..8191 granules
            const int g = G >> 11, kt = (G >> 6) & 31, l = G & 63;
            *reinterpret_cast<bf16x8*>(&WL[(size_t)G * 8]) =
                ld8(Whh + (size_t)(g * 1024 + j0 + (l & 15)) * 1024
                        + kt * 32 + (l >> 4) * 8);
        }
    }

    // ---- per-thread elementwise mapping: one j-PAIR per thread ----
    const int lb  = tid >> 3;                  // batch row 0..63
    const int lj  = (tid & 7) * 2;             // col pair 0,2,..,14
    const size_t idx  = (size_t)(bb0 + lb) * HH + j0 + lj;            // even
    const size_t xoff = (size_t)(bb0 + lb) * G4 + (size_t)(j0 + lj) * 4;  // 16B-aligned
    float c_r0, c_r1, hp0, hp1;
    if (c0 == 0) { c_r0 = c_r1 = hp0 = hp1 = 0.0f; }
    else {
        const float2 cc = *reinterpret_cast<const float2*>(&g_c[idx]);
        c_r0 = cc.x;  c_r1 = cc.y;
        // previous kernel's last write landed in buffer 0
        const unsigned hu = reinterpret_cast<const unsigned*>(g_hb[0])[idx >> 1];
        hp0 = bfu2f((unsigned short)(hu & 0xffffu));
        hp1 = bfu2f((unsigned short)(hu >> 16));
    }
    // prefetch xg for step 0 (gate-interleaved: 8 ushorts = both cols x 4 gates)
    us8 xq = *reinterpret_cast<const us8*>(g_xg + xoff);

    __syncthreads();
    const unsigned base = s_base;

    for (int s = 0; s < CHT; ++s) {
        const int t = c0 + s;
        const int wb = CHT - 1 - s;                     // write buffer
        const int rb = (s == 0) ? 0 : (CHT - s);        // read buffer (= prev write)

        f32x4 acc[4] = {};          // 4 gates, 16 batches, this kt-half
        if (t > 0) {
            // h A-frags: PLAIN cached 16B loads (L2-served; see g_hb comment)
            const __hip_bfloat16* hp = reinterpret_cast<const __hip_bfloat16*>(g_hb[rb])
                + (size_t)(bb0 + mg * 16 + row) * HH + kh * 512 + quad * 8;
            bf16x8 af[16];
#pragma unroll
            for (int kt = 0; kt < 16; ++kt)             // 16 independent loads
                af[kt] = ld8(hp + kt * 32);
            const unsigned short* wl = &WL[(size_t)(kh * 1024 + lane) * 8];
#pragma unroll
            for (int kt = 0; kt < 16; ++kt) {
                acc[0] = MF(af[kt], *(const bf16x8*)(wl + (size_t)(0 * 16384 + kt * 512)), acc[0]);
                acc[1] = MF(af[kt], *(const bf16x8*)(wl + (size_t)(1 * 16384 + kt * 512)), acc[1]);
                acc[2] = MF(af[kt], *(const bf16x8*)(wl + (size_t)(2 * 16384 + kt * 512)), acc[2]);
                acc[3] = MF(af[kt], *(const bf16x8*)(wl + (size_t)(3 * 16384 + kt * 512)), acc[3]);
            }
        }

        // ---- 2-phase kt-half reduction into gsum ----
        if (kh == 0) {
#pragma unroll
            for (int g = 0; g < 4; ++g)
#pragma unroll
                for (int r = 0; r < 4; ++r)
                    gsum[mg * 16 + quad * 4 + r][g * 16 + row] = acc[g][r];
        }
        __syncthreads();
        if (kh == 1) {
#pragma unroll
            for (int g = 0; g < 4; ++g)
#pragma unroll
                for (int r = 0; r < 4; ++r)
                    gsum[mg * 16 + quad * 4 + r][g * 16 + row] += acc[g][r];
        }
        __syncthreads();

        // ---- elementwise update: compute h, issue ONLY the h store ----
        float hv0, hv1;
        {
            const float gi0 = gsum[lb][ 0 + lj]     + bfu2f(xq[0]);
            const float gf0 = gsum[lb][16 + lj]     + bfu2f(xq[1]);
            const float gg0 = gsum[lb][32 + lj]     + bfu2f(xq[2]);
            const float go0 = gsum[lb][48 + lj]     + bfu2f(xq[3]);
            const float gi1 = gsum[lb][ 0 + lj + 1] + bfu2f(xq[4]);
            const float gf1 = gsum[lb][16 + lj + 1] + bfu2f(xq[5]);
            const float gg1 = gsum[lb][32 + lj + 1] + bfu2f(xq[6]);
            const float go1 = gsum[lb][48 + lj + 1] + bfu2f(xq[7]);
            if (t < slen[lb]) {
                c_r0 = fsig(gf0) * c_r0 + fsig(gi0) * ftanh(gg0);
                c_r1 = fsig(gf1) * c_r1 + fsig(gi1) * ftanh(gg1);
                hv0 = fsig(go0) * ftanh(c_r0);
                hv1 = fsig(go1) * ftanh(c_r1);
            } else {
                hv0 = hp0;  hv1 = hp1;             // frozen past seq end
            }
            hp0 = hv0;  hp1 = hv1;
            const unsigned hb = (unsigned)f2bu(hv0) | ((unsigned)f2bu(hv1) << 16);
            // h: agent-coherent store into this step's rotating buffer
            __hip_atomic_store(
                reinterpret_cast<unsigned*>(g_hb[wb]) + (idx >> 1), hb,
                __ATOMIC_RELAXED, __HIP_MEMORY_SCOPE_AGENT);
        }

        if (s + 1 < CHT) {
            // ---- release: drain h stores ONLY, then flag immediately ----
            __syncthreads();   // s_waitcnt vmcnt(0): only h stores in flight
            const unsigned want = base + (unsigned)s + 1u;
            if (tid == 0)
                __hip_atomic_store(&g_arrive[bh][jg][0], want,
                                   __ATOMIC_RELAXED, __HIP_MEMORY_SCOPE_AGENT);

            // ---- off the release path: seq/out stores + xq prefetch ----
            {
                const unsigned hb = (unsigned)f2bu(hv0) | ((unsigned)f2bu(hv1) << 16);
                if (layer == 0) {
                    *reinterpret_cast<unsigned*>(&g_seq[(size_t)t * BB * HH + idx]) = hb;
                } else {
                    float2 o;  o.x = hv0;  o.y = hv1;
                    *reinterpret_cast<float2*>(&out[(size_t)t * BB * HH + idx]) = o;
                }
                xq = *reinterpret_cast<const us8*>(
                    g_xg + (size_t)(s + 1) * BB * G4 + xoff);
            }

            if (wv == 0) {                                 // lane l watches block l
                unsigned v;
                do {
                    v = __hip_atomic_load(&g_arrive[bh][lane][0],
                                          __ATOMIC_RELAXED, __HIP_MEMORY_SCOPE_AGENT);
                    if (v < want) __builtin_amdgcn_s_sleep(1);
                } while (__any(v < want));
            }
            __syncthreads();
        } else {
            // final step: issue the deferred stores before kernel end
            const unsigned hb = (unsigned)f2bu(hv0) | ((unsigned)f2bu(hv1) << 16);
            if (layer == 0) {
                *reinterpret_cast<unsigned*>(&g_seq[(size_t)t * BB * HH + idx]) = hb;
            } else {
                float2 o;  o.x = hv0;  o.y = hv1;
                *reinterpret_cast<float2*>(&out[(size_t)t * BB * HH + idx]) = o;
            }
        }
    }

    // ---- chunk end: persist c ----
    float2 cc;  cc.x = c_r0;  cc.y = c_r1;
    *reinterpret_cast<float2*>(&g_c[idx]) = cc;
}

// ---------------- small utility kernels ----------------
__global__ __launch_bounds__(256) void finish_layer(float* __restrict__ hn,
                                                    float* __restrict__ cn)
{
    const int i = blockIdx.x * 256 + threadIdx.x;
    // last step of last chunk (s=CHT-1) wrote buffer 0
    const unsigned short* hfin = reinterpret_cast<const unsigned short*>(g_hb[0]);
    hn[i] = bfu2f(hfin[i]);
    cn[i] = g_c[i];
}

// =============================================================
// host launcher — plain kernel launches ONLY (graph-capture safe)
// =============================================================
extern "C" void kernel_launch(void* const* d_in, const int* in_sizes, int n_in,
                              void* d_out, int out_size, void* d_ws, size_t ws_size,
                              hipStream_t stream)
{
    const float* x        = (const float*)d_in[0];  // (T,B,D)   f32
    const float* features = (const float*)d_in[1];  // (B,F)     f32
    const float* Wih      = (const float*)d_in[2];  // (L,4H,D)  f32
    const float* Whh      = (const float*)d_in[3];  // (L,4H,H)  f32
    const float* Wfh      = (const float*)d_in[4];  // (L,4H,F)  f32
    const float* bvec     = (const float*)d_in[5];  // (L,4H)    f32
    const int*   length   = (const int*)d_in[6];    // (B,)
    float* out = (float*)d_out;                     // f32 outputs

    // one fused conversion launch: total elems = nX + 3*nW + nF
    const size_t nTot = (size_t)TT * BB * DD + 3 * ((size_t)2 * G4 * 1024)
                      + (size_t)BB * 1024;
    cvt_all<<<(int)(nTot / 1024), 256, 0, stream>>>(x, Wih, Whh, Wfh, features);

    float* out_hn = out + (size_t)TT * BB * HH;
    float* out_cn = out_hn + (size_t)2 * BB * HH;

    for (int l = 0; l < 2; ++l) {
        const size_t w_off = (size_t)l * G4 * 1024;

        gemm_featb<<<dim3(G4 / 64, BB / 128), 256, 0, stream>>>(
            w_off, bvec + (size_t)l * G4);

        for (int c0 = 0; c0 < TT; c0 += CHT) {   // 2 chunks/layer (CHT=32)
            // g_xg = g_seq[chunk] @ Wih[l]^T + g_featb  (bf16, gate-interleaved)
            gemm_xg<<<dim3(G4 / 128, CHT * BB / 128), 256, 0, stream>>>(
                (size_t)c0 * BB * DD, w_off);

            // 32 recurrent steps, one persistent launch with group barriers
            lstm_chunk<<<256, 512, 0, stream>>>(length, out, c0, l);
        }

        finish_layer<<<BB * HH / 256, 256, 0, stream>>>(
            out_hn + (size_t)l * BB * HH, out_cn + (size_t)l * BB * HH);
    }
}